// Round 1
// baseline (2534.987 us; speedup 1.0000x reference)
//
#include <hip/hip_runtime.h>
#include <math.h>

#define NN 5000
#define EE 80000
#define FIN 32
#define DD 64
#define XD 3
#define TD 6
#define PP1 256
#define PP2 32
#define HH 256
#define MM (NN + PP1 + PP2)   // 5288
#define LOG_SCALE 1.4763057f

// ---------------- workspace layout (bytes) ----------------
#define BM_OFF   0u                    // bitmask 25M bits -> 3,125,000 B (round 3,200,000)
#define CNT_OFF  3200000u              // counter (256 B slot)
#define ZEP_OFF  3200256u              // ze_pre [5000][64] f32 (zeroed accumulator)
#define AS1_OFF  4480256u              // AS1 [5000][256] f32 (zeroed accumulator)
#define ACC_OFF  9600256u              // accums: [0]=sd [1]=sp [2]=ent1 [3]=ent2
#define ZERO_BYTES 9600512u
#define EL_OFF   9600512u              // edge list (packed i*NN+j) [80000] int
#define Z_OFF    9920512u              // z [5000][64]
#define XW1_OFF  11200512u             // z @ We1 [5000][64]
#define S1_OFF   12480512u             // S1 [5000][256]
#define A2_OFF   17600512u             // A2 [256][256]
#define X2_OFF   17862656u             // x2 [256][64]
#define Y2_OFF   17928192u             // y2 [256]
#define XW2_OFF  17929216u             // x2 @ We2 [256][64]
#define S2_OFF   17994752u             // S2 [256][32]
#define ZE2_OFF  18027520u             // ze2 [256][64]
#define X3_OFF   18093056u             // x3 [32][64]
#define Y3_OFF   18101248u             // y3 [32]
#define CQ_OFF   18101376u             // c[256], q[256]

__device__ __forceinline__ float bsum256(float v, float* red) {
    int t = threadIdx.x;
    red[t] = v; __syncthreads();
    #pragma unroll
    for (int o = 128; o > 0; o >>= 1) {
        if (t < o) red[t] += red[t + o];
        __syncthreads();
    }
    float r = red[0]; __syncthreads();
    return r;
}

// c[h] = b1[h] + sum_{j<6} t_enc[j] * W1[j,h] ;  q[h] = sum_{j=1..8} W1[j,h]^2
__global__ void prep(const float* __restrict__ t, const float* __restrict__ W1,
                     const float* __restrict__ b1, float* __restrict__ cq) {
    __shared__ float te[TD];
    int h = threadIdx.x;
    if (h == 0) {
        float t0 = t[0];
        te[0] = t0 / 1e2f;
        te[1] = t0 / 1e3f;
        te[2] = t0 / 1e4f;
        te[3] = logf(t0 * 100.f + 1.f);
        te[4] = logf(t0 * 10.f + 1.f);
        te[5] = logf(t0 + 1.f);
    }
    __syncthreads();
    float c = b1[h];
    #pragma unroll
    for (int j = 0; j < TD; ++j) c = fmaf(te[j], W1[j * HH + h], c);
    float q = 0.f;
    #pragma unroll
    for (int j = 1; j < TD + XD; ++j) { float w = W1[j * HH + h]; q = fmaf(w, w, q); }
    cq[h] = c;
    cq[HH + h] = q;
}

// generic small matmul: C[i,j] = act( sum_k A[i*lda+k] * B[k*ldb+j] ) ; act0: *scale, act1: tanh then *scale
__global__ void mm(const float* __restrict__ A, int lda, const float* __restrict__ B, int ldb,
                   float* __restrict__ C, int ldc, int Mr, int Kr, int Nc, float scale, int act) {
    int gid = blockIdx.x * blockDim.x + threadIdx.x;
    if (gid >= Mr * Nc) return;
    int i = gid / Nc, j = gid - i * Nc;
    float a = 0.f;
    for (int k = 0; k < Kr; ++k) a = fmaf(A[i * lda + k], B[k * ldb + j], a);
    if (act) a = tanhf(a);
    C[i * ldc + j] = a * scale;
}

__global__ void dedupe(const int* __restrict__ adj, unsigned int* __restrict__ mask,
                       int* __restrict__ elist, int* __restrict__ cnt) {
    int e = blockIdx.x * blockDim.x + threadIdx.x;
    if (e >= EE) return;
    int i = adj[e], j = adj[EE + e];
    unsigned int key = (unsigned int)(i * NN + j);
    unsigned int bit = 1u << (key & 31u);
    unsigned int old = atomicOr(&mask[key >> 5], bit);
    if (!(old & bit)) {
        int pos = atomicAdd(cnt, 1);
        elist[pos] = (int)key;
    }
}

// ze_pre[i,:] += XW1[j,:] for each unique edge (i,j)
__global__ void scatter_ze(const int* __restrict__ elist, const int* __restrict__ cnt,
                           const float* __restrict__ XW, float* __restrict__ zep) {
    int gid = blockIdx.x * blockDim.x + threadIdx.x;
    int e = gid >> 6, d = gid & 63;
    if (e >= *cnt) return;
    int key = elist[e];
    int i = key / NN, j = key - i * NN;
    atomicAdd(&zep[i * DD + d], XW[j * DD + d]);
}

// AS1[i,:] += S1[j,:] for each unique edge (i,j)
__global__ void scatter_as(const int* __restrict__ elist, const int* __restrict__ cnt,
                           const float* __restrict__ S1, float* __restrict__ AS1) {
    int gid = blockIdx.x * blockDim.x + threadIdx.x;
    int e = gid >> 8, c = gid & 255;
    if (e >= *cnt) return;
    int key = elist[e];
    int i = key / NN, j = key - i * NN;
    atomicAdd(&AS1[i * PP1 + c], S1[j * PP1 + c]);
}

__global__ void tanh_ip(float* __restrict__ p, int n) {
    int g = blockIdx.x * blockDim.x + threadIdx.x;
    if (g < n) p[g] = tanhf(p[g]);
}

// in-place softmax over axis 0 (per column), accumulating sum of entr(S) into *ent
__global__ void softmax_col(float* __restrict__ S, int rows, int cols, float* __restrict__ ent) {
    __shared__ float red[256];
    int p = blockIdx.x, t = threadIdx.x;
    float mx = -3.0e38f;
    for (int r = t; r < rows; r += 256) mx = fmaxf(mx, S[r * cols + p]);
    red[t] = mx; __syncthreads();
    #pragma unroll
    for (int o = 128; o > 0; o >>= 1) {
        if (t < o) red[t] = fmaxf(red[t], red[t + o]);
        __syncthreads();
    }
    mx = red[0]; __syncthreads();
    float sum = 0.f;
    for (int r = t; r < rows; r += 256) sum += expf(S[r * cols + p] - mx);
    sum = bsum256(sum, red);
    float lns = logf(sum), inv = 1.f / sum;
    float en = 0.f;
    for (int r = t; r < rows; r += 256) {
        float l = S[r * cols + p];
        float s = expf(l - mx) * inv;
        S[r * cols + p] = s;
        en += s * (mx + lns - l);   // = -s*ln(s), safe for tiny s
    }
    en = bsum256(en, red);
    if (t == 0) atomicAdd(ent, en);
}

// out[j,d] = scale * sum_i S[i*scols+j] * Z[i*zcols+d]   (blockDim == zcols, grid == #j)
__global__ void pool_t(const float* __restrict__ S, int scols, const float* __restrict__ Z, int zcols,
                       int rows, float scale, float* __restrict__ out) {
    int j = blockIdx.x, d = threadIdx.x;
    float a0 = 0.f, a1 = 0.f, a2 = 0.f, a3 = 0.f;
    int i = 0;
    for (; i + 4 <= rows; i += 4) {
        a0 = fmaf(S[(i + 0) * scols + j], Z[(i + 0) * zcols + d], a0);
        a1 = fmaf(S[(i + 1) * scols + j], Z[(i + 1) * zcols + d], a1);
        a2 = fmaf(S[(i + 2) * scols + j], Z[(i + 2) * zcols + d], a2);
        a3 = fmaf(S[(i + 3) * scols + j], Z[(i + 3) * zcols + d], a3);
    }
    for (; i < rows; ++i) a0 = fmaf(S[i * scols + j], Z[i * zcols + d], a0);
    out[j * zcols + d] = (a0 + a1 + a2 + a3) * scale;
}

// out[j] = scale * sum_i yin[i] * S[i*scols+j]   (one block, thread j)
__global__ void pool_y(const float* __restrict__ S, int scols, const float* __restrict__ yin,
                       int rows, float scale, float* __restrict__ out) {
    int j = threadIdx.x;
    if (j >= scols) return;
    float a = 0.f;
    for (int i = 0; i < rows; ++i) a = fmaf(yin[i], S[i * scols + j], a);
    out[j] = a * scale;
}

// one block per row i of z_r (5288 rows); 256 threads = H
__global__ void decoder(const float* __restrict__ z, const float* __restrict__ x2,
                        const float* __restrict__ x3, const float* __restrict__ y,
                        const float* __restrict__ y2, const float* __restrict__ y3,
                        const float* __restrict__ W1, const float* __restrict__ W2,
                        const float* __restrict__ b2, const float* __restrict__ cq,
                        float* __restrict__ acc) {
    __shared__ float zrow[DD];
    __shared__ float red[256];
    int i = blockIdx.x, h = threadIdx.x;
    const float* zr = (i < NN) ? (z + i * DD)
                    : (i < NN + PP1) ? (x2 + (i - NN) * DD)
                    : (x3 + (i - NN - PP1) * DD);
    if (h < DD) zrow[h] = zr[h];
    __syncthreads();
    float a = cq[h];
    #pragma unroll
    for (int k = 0; k < DD; ++k) a = fmaf(zrow[k], W1[(TD + XD + k) * HH + h], a);
    float th = tanhf(a);
    float g1 = 1.f - th * th;
    float w2h = W2[h];
    float pu = w2h * th;
    float pg = w2h * g1 * W1[h];                      // W1[0,h]
    float pl = w2h * (-2.f * th * g1) * cq[HH + h];   // q[h]
    float su = bsum256(pu, red);
    float sg = bsum256(pg, red);
    float sl = bsum256(pl, red);
    if (h == 0) {
        float u = su + b2[0];
        float yv = (i < NN) ? y[i] : (i < NN + PP1) ? y2[i - NN] : y3[i - NN - PP1];
        float du = u - yv;
        float res = sg - sl;
        atomicAdd(&acc[0], du * du);
        atomicAdd(&acc[1], res * res);
    }
}

__global__ void finalize(const float* __restrict__ acc, float* __restrict__ out) {
    out[0] = acc[0] * (1.f / MM) + acc[1] * (1.f / MM)
           + acc[2] * (1.f / (float)(NN * PP1)) + acc[3] * (1.f / (float)(PP1 * PP2));
}

extern "C" void kernel_launch(void* const* d_in, const int* in_sizes, int n_in,
                              void* d_out, int out_size, void* d_ws, size_t ws_size,
                              hipStream_t stream) {
    const float* x0   = (const float*)d_in[0];
    const int*   adj  = (const int*)d_in[1];
    const float* t    = (const float*)d_in[2];
    const float* y    = (const float*)d_in[3];
    const float* Wenc = (const float*)d_in[4];
    const float* Wp1  = (const float*)d_in[5];
    const float* Wp2  = (const float*)d_in[6];
    const float* We1  = (const float*)d_in[7];
    const float* We2  = (const float*)d_in[8];
    const float* W1   = (const float*)d_in[9];
    const float* b1   = (const float*)d_in[10];
    const float* W2   = (const float*)d_in[11];
    const float* b2   = (const float*)d_in[12];

    char* ws = (char*)d_ws;
    unsigned int* mask = (unsigned int*)(ws + BM_OFF);
    int*   cnt   = (int*)(ws + CNT_OFF);
    float* zep   = (float*)(ws + ZEP_OFF);
    float* AS1   = (float*)(ws + AS1_OFF);
    float* acc   = (float*)(ws + ACC_OFF);
    int*   elist = (int*)(ws + EL_OFF);
    float* z     = (float*)(ws + Z_OFF);
    float* XW1   = (float*)(ws + XW1_OFF);
    float* S1    = (float*)(ws + S1_OFF);
    float* A2    = (float*)(ws + A2_OFF);
    float* x2    = (float*)(ws + X2_OFF);
    float* y2    = (float*)(ws + Y2_OFF);
    float* XW2   = (float*)(ws + XW2_OFF);
    float* S2    = (float*)(ws + S2_OFF);
    float* ze2   = (float*)(ws + ZE2_OFF);
    float* x3    = (float*)(ws + X3_OFF);
    float* y3    = (float*)(ws + Y3_OFF);
    float* cq    = (float*)(ws + CQ_OFF);

    hipMemsetAsync(ws, 0, ZERO_BYTES, stream);

    prep<<<1, 256, 0, stream>>>(t, W1, b1, cq);
    // z = tanh(x0 @ Wenc[:, :64]) * LOG_SCALE
    mm<<<(NN * DD + 255) / 256, 256, 0, stream>>>(x0, FIN, Wenc, DD + XD, z, DD, NN, FIN, DD, LOG_SCALE, 1);
    dedupe<<<(EE + 255) / 256, 256, 0, stream>>>(adj, mask, elist, cnt);
    // XW1 = z @ We1
    mm<<<(NN * DD + 255) / 256, 256, 0, stream>>>(z, DD, We1, DD, XW1, DD, NN, DD, DD, 1.f, 0);
    scatter_ze<<<(EE * 64) / 256, 256, 0, stream>>>(elist, cnt, XW1, zep);
    tanh_ip<<<(NN * DD + 255) / 256, 256, 0, stream>>>(zep, NN * DD);   // zep := ze1
    // S1 logits then softmax over rows
    mm<<<(NN * PP1 + 255) / 256, 256, 0, stream>>>(z, DD, Wp1, PP1, S1, PP1, NN, DD, PP1, LOG_SCALE, 0);
    softmax_col<<<PP1, 256, 0, stream>>>(S1, NN, PP1, &acc[2]);
    // x2 = S1^T ze1 * (256/5000);  y2 = y @ S1 * (256/5000)
    pool_t<<<PP1, DD, 0, stream>>>(S1, PP1, zep, DD, NN, 256.f / 5000.f, x2);
    pool_y<<<1, 256, 0, stream>>>(S1, PP1, y, NN, 256.f / 5000.f, y2);
    // A2 = S1^T (A S1)
    scatter_as<<<EE, 256, 0, stream>>>(elist, cnt, S1, AS1);
    pool_t<<<PP1, PP1, 0, stream>>>(S1, PP1, AS1, PP1, NN, 1.f, A2);
    // level 2
    mm<<<(PP1 * DD + 255) / 256, 256, 0, stream>>>(x2, DD, We2, DD, XW2, DD, PP1, DD, DD, 1.f, 0);
    mm<<<(PP1 * PP2 + 255) / 256, 256, 0, stream>>>(x2, DD, Wp2, PP2, S2, PP2, PP1, DD, PP2, LOG_SCALE, 0);
    softmax_col<<<PP2, 256, 0, stream>>>(S2, PP1, PP2, &acc[3]);
    mm<<<(PP1 * DD + 255) / 256, 256, 0, stream>>>(A2, PP1, XW2, DD, ze2, DD, PP1, PP1, DD, 1.f, 1);
    pool_t<<<PP2, DD, 0, stream>>>(S2, PP2, ze2, DD, PP1, 32.f / 256.f, x3);
    pool_y<<<1, 64, 0, stream>>>(S2, PP2, y2, PP1, 32.f / 256.f, y3);
    // decoder + losses
    decoder<<<MM, 256, 0, stream>>>(z, x2, x3, y, y2, y3, W1, W2, b2, cq, acc);
    finalize<<<1, 1, 0, stream>>>(acc, (float*)d_out);
}

// Round 2
// 1322.520 us; speedup vs baseline: 1.9168x; 1.9168x over previous
//
#include <hip/hip_runtime.h>
#include <math.h>

#define NN 5000
#define EE 80000
#define FIN 32
#define DD 64
#define XD 3
#define TD 6
#define PP1 256
#define PP2 32
#define HH 256
#define MM (NN + PP1 + PP2)   // 5288
#define CAP 96                // neighbor bucket capacity (Poisson mean 16 -> P(>96) ~ 0)
#define LOG_SCALE 1.4763057f

// ---------------- workspace layout (bytes) ----------------
// acc/deg/bitmask are zeroed each call. AS1 aliases the bitmask region
// (bitmask is dead after `dedupe`; stream order guarantees safety).
#define ACC_OFF   0u           // [0]=sum_data [1]=sum_pde [2]=ent1 [3]=ent2
#define DEG_OFF   256u         // deg[5000] int
#define BM_OFF    20256u       // bitmask 25M bits = 3,125,000 B
#define ZERO_BYTES 3145728u
#define AS1_OFF   20480u       // AS1 [5000][256] f32 (aliases BM; written post-dedupe)
#define BUCK_OFF  5140480u     // bucket [5000][96] int
#define ZEP_OFF   7060480u     // ze1 [5000][64]
#define Z_OFF     8340480u     // z [5000][64]
#define XW1_OFF   9620480u     // z @ We1 [5000][64]
#define S1_OFF    10900480u    // S1 [5000][256]
#define A2_OFF    16020480u    // A2 [256][256]
#define X2_OFF    16282624u    // x2 [256][64]
#define Y2_OFF    16348160u    // y2 [256]
#define XW2_OFF   16349184u    // x2 @ We2 [256][64]
#define S2_OFF    16414720u    // S2 [256][32]
#define ZE2_OFF   16447488u    // ze2 [256][64]
#define X3_OFF    16513024u    // x3 [32][64]
#define Y3_OFF    16521216u    // y3 [32]
#define CQ_OFF    16521344u    // c[256], q[256]

__device__ __forceinline__ float bsum256(float v, float* red) {
    int t = threadIdx.x;
    red[t] = v; __syncthreads();
    #pragma unroll
    for (int o = 128; o > 0; o >>= 1) {
        if (t < o) red[t] += red[t + o];
        __syncthreads();
    }
    float r = red[0]; __syncthreads();
    return r;
}

// c[h] = b1[h] + sum_{j<6} t_enc[j] * W1[j,h] ;  q[h] = sum_{j=1..8} W1[j,h]^2
__global__ void prep(const float* __restrict__ t, const float* __restrict__ W1,
                     const float* __restrict__ b1, float* __restrict__ cq) {
    __shared__ float te[TD];
    int h = threadIdx.x;
    if (h == 0) {
        float t0 = t[0];
        te[0] = t0 / 1e2f;
        te[1] = t0 / 1e3f;
        te[2] = t0 / 1e4f;
        te[3] = logf(t0 * 100.f + 1.f);
        te[4] = logf(t0 * 10.f + 1.f);
        te[5] = logf(t0 + 1.f);
    }
    __syncthreads();
    float c = b1[h];
    #pragma unroll
    for (int j = 0; j < TD; ++j) c = fmaf(te[j], W1[j * HH + h], c);
    float q = 0.f;
    #pragma unroll
    for (int j = 1; j < TD + XD; ++j) { float w = W1[j * HH + h]; q = fmaf(w, w, q); }
    cq[h] = c;
    cq[HH + h] = q;
}

// generic small matmul: C[i,j] = act( scale * sum_k A[i*lda+k] * B[k*ldb+j] )
__global__ void mm(const float* __restrict__ A, int lda, const float* __restrict__ B, int ldb,
                   float* __restrict__ C, int ldc, int Mr, int Kr, int Nc, float scale, int act) {
    int gid = blockIdx.x * blockDim.x + threadIdx.x;
    if (gid >= Mr * Nc) return;
    int i = gid / Nc, j = gid - i * Nc;
    float a = 0.f;
    for (int k = 0; k < Kr; ++k) a = fmaf(A[i * lda + k], B[k * ldb + j], a);
    if (act) a = tanhf(a);
    C[i * ldc + j] = a * scale;
}

// dedupe edges via bitmask; fill per-destination-node neighbor buckets
__global__ void dedupe(const int* __restrict__ adj, unsigned int* __restrict__ mask,
                       int* __restrict__ bucket, int* __restrict__ deg) {
    int e = blockIdx.x * blockDim.x + threadIdx.x;
    if (e >= EE) return;
    int i = adj[e], j = adj[EE + e];
    unsigned int key = (unsigned int)(i * NN + j);
    unsigned int bit = 1u << (key & 31u);
    unsigned int old = atomicOr(&mask[key >> 5], bit);
    if (!(old & bit)) {
        int slot = atomicAdd(&deg[i], 1);
        if (slot < CAP) bucket[i * CAP + slot] = j;
    }
}

// ze1[i,d] = tanh( sum_{j in N(i)} XW1[j,d] )   -- block per i, 64 threads
__global__ void gather_ze(const int* __restrict__ bucket, const int* __restrict__ deg,
                          const float* __restrict__ XW, float* __restrict__ ze) {
    int i = blockIdx.x, d = threadIdx.x;
    int n = min(deg[i], CAP);
    float a = 0.f;
    for (int s = 0; s < n; ++s) {
        int j = bucket[i * CAP + s];
        a += XW[j * DD + d];
    }
    ze[i * DD + d] = tanhf(a);
}

// AS1[i,c] = sum_{j in N(i)} S1[j,c]   -- block per i, 256 threads
__global__ void gather_as(const int* __restrict__ bucket, const int* __restrict__ deg,
                          const float* __restrict__ S1, float* __restrict__ AS1) {
    int i = blockIdx.x, c = threadIdx.x;
    int n = min(deg[i], CAP);
    float a = 0.f;
    for (int s = 0; s < n; ++s) {
        int j = bucket[i * CAP + s];
        a += S1[j * PP1 + c];
    }
    AS1[i * PP1 + c] = a;
}

// in-place softmax over axis 0 (per column) + entr accumulation + fused y-pool:
// yout[p] = yscale * sum_r S[r,p]*yin[r]
__global__ void softmax_col(float* __restrict__ S, int rows, int cols, float* __restrict__ ent,
                            const float* __restrict__ yin, float* __restrict__ yout, float yscale) {
    __shared__ float red[256];
    int p = blockIdx.x, t = threadIdx.x;
    float mx = -3.0e38f;
    for (int r = t; r < rows; r += 256) mx = fmaxf(mx, S[r * cols + p]);
    red[t] = mx; __syncthreads();
    #pragma unroll
    for (int o = 128; o > 0; o >>= 1) {
        if (t < o) red[t] = fmaxf(red[t], red[t + o]);
        __syncthreads();
    }
    mx = red[0]; __syncthreads();
    float sum = 0.f;
    for (int r = t; r < rows; r += 256) sum += expf(S[r * cols + p] - mx);
    sum = bsum256(sum, red);
    float lns = logf(sum), inv = 1.f / sum;
    float en = 0.f, ys = 0.f;
    for (int r = t; r < rows; r += 256) {
        float l = S[r * cols + p];
        float s = expf(l - mx) * inv;
        S[r * cols + p] = s;
        en += s * (mx + lns - l);          // = -s*ln(s), stable for tiny s
        ys = fmaf(s, yin[r], ys);
    }
    en = bsum256(en, red);
    ys = bsum256(ys, red);
    if (t == 0) {
        atomicAdd(ent, en);
        yout[p] = ys * yscale;
    }
}

// out[j,d] = scale * sum_i S[i*scols+j] * Z[i*zcols+d]   (blockDim == zcols, grid == #j)
__global__ void pool_t(const float* __restrict__ S, int scols, const float* __restrict__ Z, int zcols,
                       int rows, float scale, float* __restrict__ out) {
    int j = blockIdx.x, d = threadIdx.x;
    float a0 = 0.f, a1 = 0.f, a2 = 0.f, a3 = 0.f;
    int i = 0;
    for (; i + 4 <= rows; i += 4) {
        a0 = fmaf(S[(i + 0) * scols + j], Z[(i + 0) * zcols + d], a0);
        a1 = fmaf(S[(i + 1) * scols + j], Z[(i + 1) * zcols + d], a1);
        a2 = fmaf(S[(i + 2) * scols + j], Z[(i + 2) * zcols + d], a2);
        a3 = fmaf(S[(i + 3) * scols + j], Z[(i + 3) * zcols + d], a3);
    }
    for (; i < rows; ++i) a0 = fmaf(S[i * scols + j], Z[i * zcols + d], a0);
    out[j * zcols + d] = (a0 + a1 + a2 + a3) * scale;
}

// one block per row i of z_r (5288 rows); 256 threads = H
__global__ void decoder(const float* __restrict__ z, const float* __restrict__ x2,
                        const float* __restrict__ x3, const float* __restrict__ y,
                        const float* __restrict__ y2, const float* __restrict__ y3,
                        const float* __restrict__ W1, const float* __restrict__ W2,
                        const float* __restrict__ b2, const float* __restrict__ cq,
                        float* __restrict__ acc) {
    __shared__ float zrow[DD];
    __shared__ float r3[12];
    int i = blockIdx.x, h = threadIdx.x;
    const float* zr = (i < NN) ? (z + i * DD)
                    : (i < NN + PP1) ? (x2 + (i - NN) * DD)
                    : (x3 + (i - NN - PP1) * DD);
    if (h < DD) zrow[h] = zr[h];
    __syncthreads();
    float a = cq[h];
    #pragma unroll
    for (int k = 0; k < DD; ++k) a = fmaf(zrow[k], W1[(TD + XD + k) * HH + h], a);
    float th = tanhf(a);
    float g1 = 1.f - th * th;
    float w2h = W2[h];
    float pu = w2h * th;
    float pg = w2h * g1 * W1[h];                      // W1[0,h]
    float pl = w2h * (-2.f * th * g1) * cq[HH + h];   // q[h]
    // wave-level triple reduce (64-lane), then cross-wave via LDS (1 sync)
    #pragma unroll
    for (int o = 32; o > 0; o >>= 1) {
        pu += __shfl_xor(pu, o);
        pg += __shfl_xor(pg, o);
        pl += __shfl_xor(pl, o);
    }
    int wave = h >> 6, lane = h & 63;
    if (lane == 0) { r3[wave] = pu; r3[4 + wave] = pg; r3[8 + wave] = pl; }
    __syncthreads();
    if (h == 0) {
        float su = r3[0] + r3[1] + r3[2] + r3[3];
        float sg = r3[4] + r3[5] + r3[6] + r3[7];
        float sl = r3[8] + r3[9] + r3[10] + r3[11];
        float u = su + b2[0];
        float yv = (i < NN) ? y[i] : (i < NN + PP1) ? y2[i - NN] : y3[i - NN - PP1];
        float du = u - yv;
        float res = sg - sl;
        atomicAdd(&acc[0], du * du);
        atomicAdd(&acc[1], res * res);
    }
}

__global__ void finalize(const float* __restrict__ acc, float* __restrict__ out) {
    out[0] = acc[0] * (1.f / MM) + acc[1] * (1.f / MM)
           + acc[2] * (1.f / (float)(NN * PP1)) + acc[3] * (1.f / (float)(PP1 * PP2));
}

extern "C" void kernel_launch(void* const* d_in, const int* in_sizes, int n_in,
                              void* d_out, int out_size, void* d_ws, size_t ws_size,
                              hipStream_t stream) {
    const float* x0   = (const float*)d_in[0];
    const int*   adj  = (const int*)d_in[1];
    const float* t    = (const float*)d_in[2];
    const float* y    = (const float*)d_in[3];
    const float* Wenc = (const float*)d_in[4];
    const float* Wp1  = (const float*)d_in[5];
    const float* Wp2  = (const float*)d_in[6];
    const float* We1  = (const float*)d_in[7];
    const float* We2  = (const float*)d_in[8];
    const float* W1   = (const float*)d_in[9];
    const float* b1   = (const float*)d_in[10];
    const float* W2   = (const float*)d_in[11];
    const float* b2   = (const float*)d_in[12];

    char* ws = (char*)d_ws;
    float* acc   = (float*)(ws + ACC_OFF);
    int*   deg   = (int*)(ws + DEG_OFF);
    unsigned int* mask = (unsigned int*)(ws + BM_OFF);
    float* AS1   = (float*)(ws + AS1_OFF);
    int*   buck  = (int*)(ws + BUCK_OFF);
    float* zep   = (float*)(ws + ZEP_OFF);
    float* z     = (float*)(ws + Z_OFF);
    float* XW1   = (float*)(ws + XW1_OFF);
    float* S1    = (float*)(ws + S1_OFF);
    float* A2    = (float*)(ws + A2_OFF);
    float* x2    = (float*)(ws + X2_OFF);
    float* y2    = (float*)(ws + Y2_OFF);
    float* XW2   = (float*)(ws + XW2_OFF);
    float* S2    = (float*)(ws + S2_OFF);
    float* ze2   = (float*)(ws + ZE2_OFF);
    float* x3    = (float*)(ws + X3_OFF);
    float* y3    = (float*)(ws + Y3_OFF);
    float* cq    = (float*)(ws + CQ_OFF);

    hipMemsetAsync(ws, 0, ZERO_BYTES, stream);

    prep<<<1, 256, 0, stream>>>(t, W1, b1, cq);
    // z = tanh(x0 @ Wenc[:, :64]) * LOG_SCALE
    mm<<<(NN * DD + 255) / 256, 256, 0, stream>>>(x0, FIN, Wenc, DD + XD, z, DD, NN, FIN, DD, LOG_SCALE, 1);
    dedupe<<<(EE + 255) / 256, 256, 0, stream>>>(adj, mask, buck, deg);
    // XW1 = z @ We1
    mm<<<(NN * DD + 255) / 256, 256, 0, stream>>>(z, DD, We1, DD, XW1, DD, NN, DD, DD, 1.f, 0);
    // ze1 = tanh(A @ XW1)  (gather, fused tanh)
    gather_ze<<<NN, DD, 0, stream>>>(buck, deg, XW1, zep);
    // S1 logits then softmax over rows (+ ent + y2)
    mm<<<(NN * PP1 + 255) / 256, 256, 0, stream>>>(z, DD, Wp1, PP1, S1, PP1, NN, DD, PP1, LOG_SCALE, 0);
    softmax_col<<<PP1, 256, 0, stream>>>(S1, NN, PP1, &acc[2], y, y2, 256.f / 5000.f);
    // x2 = S1^T ze1 * (256/5000)
    pool_t<<<PP1, DD, 0, stream>>>(S1, PP1, zep, DD, NN, 256.f / 5000.f, x2);
    // A2 = S1^T (A S1)
    gather_as<<<NN, PP1, 0, stream>>>(buck, deg, S1, AS1);
    pool_t<<<PP1, PP1, 0, stream>>>(S1, PP1, AS1, PP1, NN, 1.f, A2);
    // level 2
    mm<<<(PP1 * DD + 255) / 256, 256, 0, stream>>>(x2, DD, We2, DD, XW2, DD, PP1, DD, DD, 1.f, 0);
    mm<<<(PP1 * PP2 + 255) / 256, 256, 0, stream>>>(x2, DD, Wp2, PP2, S2, PP2, PP1, DD, PP2, LOG_SCALE, 0);
    softmax_col<<<PP2, 256, 0, stream>>>(S2, PP1, PP2, &acc[3], y2, y3, 32.f / 256.f);
    mm<<<(PP1 * DD + 255) / 256, 256, 0, stream>>>(A2, PP1, XW2, DD, ze2, DD, PP1, PP1, DD, 1.f, 1);
    pool_t<<<PP2, DD, 0, stream>>>(S2, PP2, ze2, DD, PP1, 32.f / 256.f, x3);
    // decoder + losses
    decoder<<<MM, 256, 0, stream>>>(z, x2, x3, y, y2, y3, W1, W2, b2, cq, acc);
    finalize<<<1, 1, 0, stream>>>(acc, (float*)d_out);
}

// Round 3
// 644.333 us; speedup vs baseline: 3.9343x; 2.0525x over previous
//
#include <hip/hip_runtime.h>
#include <math.h>

#define NN 5000
#define EE 80000
#define FIN 32
#define DD 64
#define XD 3
#define TD 6
#define PP1 256
#define PP2 32
#define HH 256
#define MM (NN + PP1 + PP2)   // 5288
#define CAP 64                // neighbor bucket capacity (Poisson mean 16; P(deg>64) ~ 1e-18)
#define CHUNKS 200            // softmax row chunks (25 rows each)
#define LOG_SCALE 1.4763057f

// ---------------- workspace layout (bytes) ----------------
// Zeroed region [0, ZERO_BYTES): accumulators + bitmask.
// PART..Y3 alias the bitmask region (bitmask dead after `dedupe`; all aliased
// buffers are fully written after dedupe and before their readers).
#define ACC_OFF   0u           // [0]=sum_data [1]=sum_pde [2]=ent1 [3]=ent2
#define DEG_OFF   256u         // deg[5000] int -> 20256
#define Y2A_OFF   20256u       // y2 accumulator [256] -> 21280
#define X2_OFF    21280u       // x2 [256][64] (atomic split-K dest) -> 86816
#define A2_OFF    86816u       // A2 [256][256] (atomic split-K dest) -> 348960
#define BM_OFF    348960u      // bitmask 25M bits = 3,125,000 B -> 3,473,960
#define ZERO_BYTES 3473960u
// aliases inside BM region (post-dedupe lifetime):
#define PART_OFF  348960u      // [200][2][256] f32 -> 758560
#define CSTAT_OFF 758560u      // [256] mx+ln(sum) -> 759584
#define Y2_OFF    759584u      // y2 [256] -> 760608
#define XW2_OFF   760608u      // x2 @ We2 [256][64] -> 826144
#define S2_OFF    826144u      // S2 [256][32] -> 858912
#define ZE2_OFF   858912u      // ze2 [256][64] -> 924448
#define X3_OFF    924448u      // x3 [32][64] -> 932640
#define Y3_OFF    932640u      // y3 [32] -> 932768
// non-zeroed:
#define BUCK_OFF  3473984u     // bucket [5000][64] int -> 4753984
#define ZEP_OFF   4753984u     // zsum then ze1 [5000][64] -> 6033984
#define Z_OFF     6033984u     // z [5000][64] -> 7313984
#define S1_OFF    7313984u     // S1 [5000][256] -> 12433984
#define AS1_OFF   12433984u    // AS1 [5000][256] -> 17553984
#define CQ_OFF    17553984u    // c[256], q[256] -> 17556032

__device__ __forceinline__ float bsum256(float v, float* red) {
    int t = threadIdx.x;
    red[t] = v; __syncthreads();
    #pragma unroll
    for (int o = 128; o > 0; o >>= 1) {
        if (t < o) red[t] += red[t + o];
        __syncthreads();
    }
    float r = red[0]; __syncthreads();
    return r;
}

// c[h] = b1[h] + sum_{j<6} t_enc[j] * W1[j,h] ;  q[h] = sum_{j=1..8} W1[j,h]^2
__global__ void prep(const float* __restrict__ t, const float* __restrict__ W1,
                     const float* __restrict__ b1, float* __restrict__ cq) {
    __shared__ float te[TD];
    int h = threadIdx.x;
    if (h == 0) {
        float t0 = t[0];
        te[0] = t0 / 1e2f;
        te[1] = t0 / 1e3f;
        te[2] = t0 / 1e4f;
        te[3] = logf(t0 * 100.f + 1.f);
        te[4] = logf(t0 * 10.f + 1.f);
        te[5] = logf(t0 + 1.f);
    }
    __syncthreads();
    float c = b1[h];
    #pragma unroll
    for (int j = 0; j < TD; ++j) c = fmaf(te[j], W1[j * HH + h], c);
    float q = 0.f;
    #pragma unroll
    for (int j = 1; j < TD + XD; ++j) { float w = W1[j * HH + h]; q = fmaf(w, w, q); }
    cq[h] = c;
    cq[HH + h] = q;
}

// generic small matmul: C[i,j] = act( scale * sum_k A[i*lda+k] * B[k*ldb+j] )
__global__ void mm(const float* __restrict__ A, int lda, const float* __restrict__ B, int ldb,
                   float* __restrict__ C, int ldc, int Mr, int Kr, int Nc, float scale, int act) {
    int gid = blockIdx.x * blockDim.x + threadIdx.x;
    if (gid >= Mr * Nc) return;
    int i = gid / Nc, j = gid - i * Nc;
    float a = 0.f;
    for (int k = 0; k < Kr; ++k) a = fmaf(A[i * lda + k], B[k * ldb + j], a);
    if (act) a = tanhf(a);
    C[i * ldc + j] = a * scale;
}

// dedupe edges via bitmask; fill per-destination-node neighbor buckets
__global__ void dedupe(const int* __restrict__ adj, unsigned int* __restrict__ mask,
                       int* __restrict__ bucket, int* __restrict__ deg) {
    int e = blockIdx.x * blockDim.x + threadIdx.x;
    if (e >= EE) return;
    int i = adj[e], j = adj[EE + e];
    unsigned int key = (unsigned int)(i * NN + j);
    unsigned int bit = 1u << (key & 31u);
    unsigned int old = atomicOr(&mask[key >> 5], bit);
    if (!(old & bit)) {
        int slot = atomicAdd(&deg[i], 1);
        if (slot < CAP) bucket[i * CAP + slot] = j;
    }
}

// zsum[i,d] = sum_{j in N(i)} z[j,d]   -- block per i, 64 threads
__global__ void gather_z(const int* __restrict__ bucket, const int* __restrict__ deg,
                         const float* __restrict__ z, float* __restrict__ zsum) {
    int i = blockIdx.x, d = threadIdx.x;
    int n = min(deg[i], CAP);
    float a = 0.f;
    for (int s = 0; s < n; ++s) {
        int j = bucket[i * CAP + s];
        a += z[j * DD + d];
    }
    zsum[i * DD + d] = a;
}

// in-place X := tanh(X @ B), X [NN][64], B [64][64]; 4 rows per block
__global__ void mm_ip_tanh(float* __restrict__ X, const float* __restrict__ B) {
    __shared__ float a[4][DD];
    int r0 = blockIdx.x << 2;
    int lr = threadIdx.x >> 6, lc = threadIdx.x & 63;
    a[lr][lc] = X[(r0 + lr) * DD + lc];
    __syncthreads();
    float s = 0.f;
    #pragma unroll
    for (int k = 0; k < DD; ++k) s = fmaf(a[lr][k], B[k * DD + lc], s);
    X[(r0 + lr) * DD + lc] = tanhf(s);
}

// AS1[i,c] = sum_{j in N(i)} S1[j,c]   -- block per i, 256 threads
__global__ void gather_as(const int* __restrict__ bucket, const int* __restrict__ deg,
                          const float* __restrict__ S1, float* __restrict__ AS1) {
    int i = blockIdx.x, c = threadIdx.x;
    int n = min(deg[i], CAP);
    float a = 0.f;
    for (int s = 0; s < n; ++s) {
        int j = bucket[i * CAP + s];
        a += S1[j * PP1 + c];
    }
    AS1[i * PP1 + c] = a;
}

// ---- coalesced column softmax over S1 [5000][256] ----
// pass 1: per-25-row-chunk column max & expsum (threads = columns -> coalesced)
__global__ void smax_part(const float* __restrict__ S, float* __restrict__ part) {
    int c = threadIdx.x, ch = blockIdx.x;
    const float* p = S + ch * 25 * PP1 + c;
    float m = -3.0e38f;
    #pragma unroll
    for (int r = 0; r < 25; ++r) m = fmaxf(m, p[r * PP1]);
    float s = 0.f;
    #pragma unroll
    for (int r = 0; r < 25; ++r) s += expf(p[r * PP1] - m);
    part[ch * 512 + c] = m;
    part[ch * 512 + 256 + c] = s;
}

// pass 2: combine chunk partials -> cstat[c] = colmax + ln(colsum)
__global__ void smax_finish(const float* __restrict__ part, float* __restrict__ cstat) {
    int c = threadIdx.x;
    float M = -3.0e38f;
    for (int ch = 0; ch < CHUNKS; ++ch) M = fmaxf(M, part[ch * 512 + c]);
    float S = 0.f;
    for (int ch = 0; ch < CHUNKS; ++ch) S += part[ch * 512 + 256 + c] * expf(part[ch * 512 + c] - M);
    cstat[c] = M + logf(S);
}

// pass 3: normalize in place + entropy + y-pool accumulation (64x64 tiles)
__global__ void smax_norm(float* __restrict__ S, const float* __restrict__ cstat,
                          const float* __restrict__ y, float* __restrict__ y2acc,
                          float* __restrict__ ent) {
    __shared__ float red[256];
    __shared__ float ybuf[4][64];
    int rt = blockIdx.x % 79, ct = blockIdx.x / 79;
    int lc = threadIdx.x & 63, lr = threadIdx.x >> 6;
    int c = (ct << 6) + lc;
    float mxlns = cstat[c];
    float en = 0.f, ys = 0.f;
    #pragma unroll
    for (int k = 0; k < 16; ++k) {
        int r = (rt << 6) + (k << 2) + lr;
        if (r < NN) {
            float v = S[r * PP1 + c];
            float s = expf(v - mxlns);       // = exp(v - mx) / sum
            S[r * PP1 + c] = s;
            en += s * (mxlns - v);           // = -s*ln(s)
            ys = fmaf(s, y[r], ys);
        }
    }
    ybuf[lr][lc] = ys;
    en = bsum256(en, red);                   // syncs cover ybuf visibility
    if (threadIdx.x == 0) atomicAdd(ent, en);
    if (lr == 0) atomicAdd(&y2acc[c], ybuf[0][lc] + ybuf[1][lc] + ybuf[2][lc] + ybuf[3][lc]);
}

__global__ void scale_y2(const float* __restrict__ a, float* __restrict__ y2) {
    y2[threadIdx.x] = a[threadIdx.x] * (256.f / 5000.f);
}

// split-K TN GEMM: C[M][N] += scale * A^T B, A: K x M row-major, B: K x N row-major.
// grid.x = (M/64)*(N/64), grid.y = K chunks; 256 threads, 4x4 microtile; atomic accumulate.
__global__ void gemm_tn(const float* __restrict__ A, const float* __restrict__ B,
                        float* __restrict__ C, int M, int N, int K, int kchunk, float scale) {
    __shared__ float sa[32][64];
    __shared__ float sb[32][64];
    int tilesN = N >> 6;
    int tm = (blockIdx.x / tilesN) << 6;
    int tn = (blockIdx.x % tilesN) << 6;
    int k0 = blockIdx.y * kchunk;
    int k1 = min(k0 + kchunk, K);
    int tid = threadIdx.x;
    int tx = (tid & 15) << 2;   // n offset
    int ty = (tid >> 4) << 2;   // m offset
    float acc[4][4] = {};
    for (int kb = k0; kb < k1; kb += 32) {
        #pragma unroll
        for (int t = 0; t < 8; ++t) {
            int idx = tid + (t << 8);
            int r = idx >> 6, cc = idx & 63;
            int k = kb + r;
            sa[r][cc] = (k < k1) ? A[k * M + tm + cc] : 0.f;
            sb[r][cc] = (k < k1) ? B[k * N + tn + cc] : 0.f;
        }
        __syncthreads();
        #pragma unroll
        for (int kk = 0; kk < 32; ++kk) {
            float4 av = *(const float4*)&sa[kk][ty];
            float4 bv = *(const float4*)&sb[kk][tx];
            acc[0][0] = fmaf(av.x, bv.x, acc[0][0]);
            acc[0][1] = fmaf(av.x, bv.y, acc[0][1]);
            acc[0][2] = fmaf(av.x, bv.z, acc[0][2]);
            acc[0][3] = fmaf(av.x, bv.w, acc[0][3]);
            acc[1][0] = fmaf(av.y, bv.x, acc[1][0]);
            acc[1][1] = fmaf(av.y, bv.y, acc[1][1]);
            acc[1][2] = fmaf(av.y, bv.z, acc[1][2]);
            acc[1][3] = fmaf(av.y, bv.w, acc[1][3]);
            acc[2][0] = fmaf(av.z, bv.x, acc[2][0]);
            acc[2][1] = fmaf(av.z, bv.y, acc[2][1]);
            acc[2][2] = fmaf(av.z, bv.z, acc[2][2]);
            acc[2][3] = fmaf(av.z, bv.w, acc[2][3]);
            acc[3][0] = fmaf(av.w, bv.x, acc[3][0]);
            acc[3][1] = fmaf(av.w, bv.y, acc[3][1]);
            acc[3][2] = fmaf(av.w, bv.z, acc[3][2]);
            acc[3][3] = fmaf(av.w, bv.w, acc[3][3]);
        }
        __syncthreads();
    }
    #pragma unroll
    for (int i = 0; i < 4; ++i)
        #pragma unroll
        for (int j = 0; j < 4; ++j)
            atomicAdd(&C[(tm + ty + i) * N + tn + tx + j], acc[i][j] * scale);
}

// small column softmax (used for S2: 256 rows x 32 cols) + entr + y-pool
__global__ void softmax_col(float* __restrict__ S, int rows, int cols, float* __restrict__ ent,
                            const float* __restrict__ yin, float* __restrict__ yout, float yscale) {
    __shared__ float red[256];
    int p = blockIdx.x, t = threadIdx.x;
    float mx = -3.0e38f;
    for (int r = t; r < rows; r += 256) mx = fmaxf(mx, S[r * cols + p]);
    red[t] = mx; __syncthreads();
    #pragma unroll
    for (int o = 128; o > 0; o >>= 1) {
        if (t < o) red[t] = fmaxf(red[t], red[t + o]);
        __syncthreads();
    }
    mx = red[0]; __syncthreads();
    float sum = 0.f;
    for (int r = t; r < rows; r += 256) sum += expf(S[r * cols + p] - mx);
    sum = bsum256(sum, red);
    float lns = logf(sum), inv = 1.f / sum;
    float en = 0.f, ys = 0.f;
    for (int r = t; r < rows; r += 256) {
        float l = S[r * cols + p];
        float s = expf(l - mx) * inv;
        S[r * cols + p] = s;
        en += s * (mx + lns - l);
        ys = fmaf(s, yin[r], ys);
    }
    en = bsum256(en, red);
    ys = bsum256(ys, red);
    if (t == 0) {
        atomicAdd(ent, en);
        yout[p] = ys * yscale;
    }
}

// out[j,d] = scale * sum_i S[i*scols+j] * Z[i*zcols+d]   (small; used for x3)
__global__ void pool_t(const float* __restrict__ S, int scols, const float* __restrict__ Z, int zcols,
                       int rows, float scale, float* __restrict__ out) {
    int j = blockIdx.x, d = threadIdx.x;
    float a = 0.f;
    for (int i = 0; i < rows; ++i) a = fmaf(S[i * scols + j], Z[i * zcols + d], a);
    out[j * zcols + d] = a * scale;
}

// one block per row i of z_r (5288 rows); 256 threads = H
__global__ void decoder(const float* __restrict__ z, const float* __restrict__ x2,
                        const float* __restrict__ x3, const float* __restrict__ y,
                        const float* __restrict__ y2, const float* __restrict__ y3,
                        const float* __restrict__ W1, const float* __restrict__ W2,
                        const float* __restrict__ b2, const float* __restrict__ cq,
                        float* __restrict__ acc) {
    __shared__ float zrow[DD];
    __shared__ float r3[12];
    int i = blockIdx.x, h = threadIdx.x;
    const float* zr = (i < NN) ? (z + i * DD)
                    : (i < NN + PP1) ? (x2 + (i - NN) * DD)
                    : (x3 + (i - NN - PP1) * DD);
    if (h < DD) zrow[h] = zr[h];
    __syncthreads();
    float a = cq[h];
    #pragma unroll
    for (int k = 0; k < DD; ++k) a = fmaf(zrow[k], W1[(TD + XD + k) * HH + h], a);
    float th = tanhf(a);
    float g1 = 1.f - th * th;
    float w2h = W2[h];
    float pu = w2h * th;
    float pg = w2h * g1 * W1[h];                      // W1[0,h]
    float pl = w2h * (-2.f * th * g1) * cq[HH + h];   // q[h]
    #pragma unroll
    for (int o = 32; o > 0; o >>= 1) {
        pu += __shfl_xor(pu, o);
        pg += __shfl_xor(pg, o);
        pl += __shfl_xor(pl, o);
    }
    int wave = h >> 6, lane = h & 63;
    if (lane == 0) { r3[wave] = pu; r3[4 + wave] = pg; r3[8 + wave] = pl; }
    __syncthreads();
    if (h == 0) {
        float su = r3[0] + r3[1] + r3[2] + r3[3];
        float sg = r3[4] + r3[5] + r3[6] + r3[7];
        float sl = r3[8] + r3[9] + r3[10] + r3[11];
        float u = su + b2[0];
        float yv = (i < NN) ? y[i] : (i < NN + PP1) ? y2[i - NN] : y3[i - NN - PP1];
        float du = u - yv;
        float res = sg - sl;
        atomicAdd(&acc[0], du * du);
        atomicAdd(&acc[1], res * res);
    }
}

__global__ void finalize(const float* __restrict__ acc, float* __restrict__ out) {
    out[0] = acc[0] * (1.f / MM) + acc[1] * (1.f / MM)
           + acc[2] * (1.f / (float)(NN * PP1)) + acc[3] * (1.f / (float)(PP1 * PP2));
}

extern "C" void kernel_launch(void* const* d_in, const int* in_sizes, int n_in,
                              void* d_out, int out_size, void* d_ws, size_t ws_size,
                              hipStream_t stream) {
    const float* x0   = (const float*)d_in[0];
    const int*   adj  = (const int*)d_in[1];
    const float* t    = (const float*)d_in[2];
    const float* y    = (const float*)d_in[3];
    const float* Wenc = (const float*)d_in[4];
    const float* Wp1  = (const float*)d_in[5];
    const float* Wp2  = (const float*)d_in[6];
    const float* We1  = (const float*)d_in[7];
    const float* We2  = (const float*)d_in[8];
    const float* W1   = (const float*)d_in[9];
    const float* b1   = (const float*)d_in[10];
    const float* W2   = (const float*)d_in[11];
    const float* b2   = (const float*)d_in[12];

    char* ws = (char*)d_ws;
    float* acc   = (float*)(ws + ACC_OFF);
    int*   deg   = (int*)(ws + DEG_OFF);
    float* y2acc = (float*)(ws + Y2A_OFF);
    float* x2    = (float*)(ws + X2_OFF);
    float* A2    = (float*)(ws + A2_OFF);
    unsigned int* mask = (unsigned int*)(ws + BM_OFF);
    float* part  = (float*)(ws + PART_OFF);
    float* cstat = (float*)(ws + CSTAT_OFF);
    float* y2    = (float*)(ws + Y2_OFF);
    float* XW2   = (float*)(ws + XW2_OFF);
    float* S2    = (float*)(ws + S2_OFF);
    float* ze2   = (float*)(ws + ZE2_OFF);
    float* x3    = (float*)(ws + X3_OFF);
    float* y3    = (float*)(ws + Y3_OFF);
    int*   buck  = (int*)(ws + BUCK_OFF);
    float* zep   = (float*)(ws + ZEP_OFF);
    float* z     = (float*)(ws + Z_OFF);
    float* S1    = (float*)(ws + S1_OFF);
    float* AS1   = (float*)(ws + AS1_OFF);
    float* cq    = (float*)(ws + CQ_OFF);

    hipMemsetAsync(ws, 0, ZERO_BYTES, stream);

    prep<<<1, 256, 0, stream>>>(t, W1, b1, cq);
    // z = tanh(x0 @ Wenc[:, :64]) * LOG_SCALE
    mm<<<(NN * DD + 255) / 256, 256, 0, stream>>>(x0, FIN, Wenc, DD + XD, z, DD, NN, FIN, DD, LOG_SCALE, 1);
    dedupe<<<(EE + 255) / 256, 256, 0, stream>>>(adj, mask, buck, deg);
    // ze1 = tanh((A @ z) @ We1)  (reassociated; saves XW1 buffer)
    gather_z<<<NN, DD, 0, stream>>>(buck, deg, z, zep);
    mm_ip_tanh<<<NN / 4, 256, 0, stream>>>(zep, We1);
    // S1 logits then coalesced column softmax (+ ent + y2 accumulation)
    mm<<<(NN * PP1 + 255) / 256, 256, 0, stream>>>(z, DD, Wp1, PP1, S1, PP1, NN, DD, PP1, LOG_SCALE, 0);
    smax_part<<<CHUNKS, 256, 0, stream>>>(S1, part);
    smax_finish<<<1, 256, 0, stream>>>(part, cstat);
    smax_norm<<<79 * 4, 256, 0, stream>>>(S1, cstat, y, y2acc, &acc[2]);
    scale_y2<<<1, 256, 0, stream>>>(y2acc, y2);
    // x2 = S1^T ze1 * (256/5000)   [split-K GEMM, atomic accumulate into zeroed x2]
    gemm_tn<<<dim3(4, 32), 256, 0, stream>>>(S1, zep, x2, PP1, DD, NN, 157, 256.f / 5000.f);
    // A2 = S1^T (A S1)
    gather_as<<<NN, PP1, 0, stream>>>(buck, deg, S1, AS1);
    gemm_tn<<<dim3(16, 16), 256, 0, stream>>>(S1, AS1, A2, PP1, PP1, NN, 313, 1.f);
    // level 2
    mm<<<(PP1 * DD + 255) / 256, 256, 0, stream>>>(x2, DD, We2, DD, XW2, DD, PP1, DD, DD, 1.f, 0);
    mm<<<(PP1 * PP2 + 255) / 256, 256, 0, stream>>>(x2, DD, Wp2, PP2, S2, PP2, PP1, DD, PP2, LOG_SCALE, 0);
    softmax_col<<<PP2, 256, 0, stream>>>(S2, PP1, PP2, &acc[3], y2, y3, 32.f / 256.f);
    mm<<<(PP1 * DD + 255) / 256, 256, 0, stream>>>(A2, PP1, XW2, DD, ze2, DD, PP1, PP1, DD, 1.f, 1);
    pool_t<<<PP2, DD, 0, stream>>>(S2, PP2, ze2, DD, PP1, 32.f / 256.f, x3);
    // decoder + losses
    decoder<<<MM, 256, 0, stream>>>(z, x2, x3, y, y2, y3, W1, W2, b2, cq, acc);
    finalize<<<1, 1, 0, stream>>>(acc, (float*)d_out);
}

// Round 4
// 317.791 us; speedup vs baseline: 7.9769x; 2.0275x over previous
//
#include <hip/hip_runtime.h>
#include <math.h>

#define NN 5000
#define EE 80000
#define FIN 32
#define DD 64
#define XD 3
#define TD 6
#define PP1 256
#define PP2 32
#define HH 256
#define MM (NN + PP1 + PP2)   // 5288
#define CAP 64                // neighbor bucket capacity (Poisson mean 16; P(deg>64) ~ 1e-18)
#define CHUNKS 200            // softmax row chunks (25 rows each)
#define LOG_SCALE 1.4763057f
#define Y2SCALE (256.f / 5000.f)

// ---------------- workspace layout (bytes) ----------------
// Zeroed region [0, ZERO_BYTES): accumulators + bitmask.
// PART..Y3 alias the bitmask region (bitmask dead after stage0/dedupe).
#define ACC_OFF   0u           // [2]=ent1 [3]=ent2 (0/1 unused now)
#define DEG_OFF   256u         // deg[5000] int -> 20256
#define Y2A_OFF   20256u       // y2 accumulator [256] -> 21280
#define X2_OFF    21280u       // x2 [256][64] (atomic split-K dest) -> 86816
#define A2_OFF    86816u       // A2 [256][256] (atomic split-K dest) -> 348960
#define BM_OFF    348960u      // bitmask 25M bits = 3,125,000 B -> 3,473,960
#define ZERO_BYTES 3473960u
// aliases inside BM region (post-dedupe lifetime):
#define PART_OFF  348960u      // [200][2][256] f32 -> 758560
#define CSTAT_OFF 758560u      // [256] mx+ln(sum) -> 759584
#define XW2_OFF   760608u      // x2 @ We2 [256][64] -> 826144
#define S2_OFF    826144u      // S2 [256][32] -> 858912
#define ZE2_OFF   858912u      // ze2 [256][64] -> 924448
#define X3_OFF    924448u      // x3 [32][64] -> 932640
#define Y3_OFF    932640u      // y3 [32] -> 932768
// non-zeroed:
#define BUCK_OFF  3473984u     // bucket [5000][64] int -> 4753984
#define ZEP_OFF   4753984u     // zsum then ze1 [5000][64] -> 6033984
#define Z_OFF     6033984u     // z [5000][64] -> 7313984
#define S1_OFF    7313984u     // S1 [5000][256] -> 12433984
#define AS1_OFF   12433984u    // AS1 [5000][256] -> 17553984
#define CQ_OFF    17553984u    // c[256], q[256] -> 17556032
#define DRES_OFF  17556032u    // dres [5288][2] -> 17598336

__device__ __forceinline__ float bsum256(float v, float* red) {
    int t = threadIdx.x;
    red[t] = v; __syncthreads();
    #pragma unroll
    for (int o = 128; o > 0; o >>= 1) {
        if (t < o) red[t] += red[t + o];
        __syncthreads();
    }
    float r = red[0]; __syncthreads();
    return r;
}

// fused: encoder GEMM (blocks 0..1249) | edge dedupe (1250..1562) | prep c/q (1563)
__global__ void stage0(const float* __restrict__ x0, const float* __restrict__ Wenc,
                       float* __restrict__ z,
                       const int* __restrict__ adj, unsigned int* __restrict__ mask,
                       int* __restrict__ bucket, int* __restrict__ deg,
                       const float* __restrict__ t, const float* __restrict__ W1,
                       const float* __restrict__ b1, float* __restrict__ cq) {
    __shared__ float te[TD];
    int b = blockIdx.x;
    if (b < 1250) {
        int gid = b * 256 + threadIdx.x;
        int i = gid >> 6, j = gid & 63;
        float s = 0.f;
        #pragma unroll
        for (int k = 0; k < FIN; ++k) s = fmaf(x0[i * FIN + k], Wenc[k * (DD + XD) + j], s);
        z[i * DD + j] = tanhf(s) * LOG_SCALE;
    } else if (b < 1563) {
        int e = (b - 1250) * 256 + threadIdx.x;
        if (e < EE) {
            int i = adj[e], j = adj[EE + e];
            unsigned int key = (unsigned int)(i * NN + j);
            unsigned int bit = 1u << (key & 31u);
            unsigned int old = atomicOr(&mask[key >> 5], bit);
            if (!(old & bit)) {
                int slot = atomicAdd(&deg[i], 1);
                if (slot < CAP) bucket[i * CAP + slot] = j;
            }
        }
    } else {
        int h = threadIdx.x;
        if (h == 0) {
            float t0 = t[0];
            te[0] = t0 / 1e2f;
            te[1] = t0 / 1e3f;
            te[2] = t0 / 1e4f;
            te[3] = logf(t0 * 100.f + 1.f);
            te[4] = logf(t0 * 10.f + 1.f);
            te[5] = logf(t0 + 1.f);
        }
        __syncthreads();
        float c = b1[h];
        #pragma unroll
        for (int j = 0; j < TD; ++j) c = fmaf(te[j], W1[j * HH + h], c);
        float q = 0.f;
        #pragma unroll
        for (int j = 1; j < TD + XD; ++j) { float w = W1[j * HH + h]; q = fmaf(w, w, q); }
        cq[h] = c;
        cq[HH + h] = q;
    }
}

// small matmul, compile-time K (full unroll): C[i,j] = act(scale * sum_k A[i,k]*B[k,j])
template<int KK, int ACT>
__global__ void mm_t(const float* __restrict__ A, int lda, const float* __restrict__ B, int ldb,
                     float* __restrict__ C, int ldc, int Mr, int Nc, float scale) {
    int gid = blockIdx.x * blockDim.x + threadIdx.x;
    if (gid >= Mr * Nc) return;
    int i = gid / Nc, j = gid - i * Nc;
    const float* a = A + i * lda;
    const float* bp = B + j;
    float s = 0.f;
    #pragma unroll
    for (int k = 0; k < KK; ++k) s = fmaf(a[k], bp[k * ldb], s);
    if (ACT) s = tanhf(s);
    C[i * ldc + j] = s * scale;
}

// ze2 = tanh(A2 @ XW2): A2 [256][256], XW2 [256][64]
__global__ void mm_k256_tanh(const float* __restrict__ A, const float* __restrict__ B,
                             float* __restrict__ C) {
    int gid = blockIdx.x * blockDim.x + threadIdx.x;
    int i = gid >> 6, j = gid & 63;
    const float* a = A + i * PP1;
    float s = 0.f;
    #pragma unroll 16
    for (int k = 0; k < PP1; ++k) s = fmaf(a[k], B[k * DD + j], s);
    C[i * DD + j] = tanhf(s);
}

// zsum[i,d] = sum_{j in N(i)} z[j,d]   -- block per i, 64 threads, 4-wide unroll
__global__ void gather_z(const int* __restrict__ bucket, const int* __restrict__ deg,
                         const float* __restrict__ z, float* __restrict__ zsum) {
    int i = blockIdx.x, d = threadIdx.x;
    int n = min(deg[i], CAP);
    const int* bk = bucket + i * CAP;
    float a0 = 0.f, a1 = 0.f, a2 = 0.f, a3 = 0.f;
    int s = 0;
    for (; s + 4 <= n; s += 4) {
        int j0 = bk[s], j1 = bk[s + 1], j2 = bk[s + 2], j3 = bk[s + 3];
        a0 += z[j0 * DD + d];
        a1 += z[j1 * DD + d];
        a2 += z[j2 * DD + d];
        a3 += z[j3 * DD + d];
    }
    for (; s < n; ++s) a0 += z[bk[s] * DD + d];
    zsum[i * DD + d] = (a0 + a1) + (a2 + a3);
}

// in-place X := tanh(X @ B), X [NN][64], B [64][64]; 4 rows per block
__global__ void mm_ip_tanh(float* __restrict__ X, const float* __restrict__ B) {
    __shared__ float a[4][DD];
    int r0 = blockIdx.x << 2;
    int lr = threadIdx.x >> 6, lc = threadIdx.x & 63;
    a[lr][lc] = X[(r0 + lr) * DD + lc];
    __syncthreads();
    float s = 0.f;
    #pragma unroll
    for (int k = 0; k < DD; ++k) s = fmaf(a[lr][k], B[k * DD + lc], s);
    X[(r0 + lr) * DD + lc] = tanhf(s);
}

// AS1[i,c] = sum_{j in N(i)} S1[j,c]   -- block per i, 256 threads, 4-wide unroll
__global__ void gather_as(const int* __restrict__ bucket, const int* __restrict__ deg,
                          const float* __restrict__ S1, float* __restrict__ AS1) {
    int i = blockIdx.x, c = threadIdx.x;
    int n = min(deg[i], CAP);
    const int* bk = bucket + i * CAP;
    float a0 = 0.f, a1 = 0.f, a2 = 0.f, a3 = 0.f;
    int s = 0;
    for (; s + 4 <= n; s += 4) {
        int j0 = bk[s], j1 = bk[s + 1], j2 = bk[s + 2], j3 = bk[s + 3];
        a0 += S1[j0 * PP1 + c];
        a1 += S1[j1 * PP1 + c];
        a2 += S1[j2 * PP1 + c];
        a3 += S1[j3 * PP1 + c];
    }
    for (; s < n; ++s) a0 += S1[bk[s] * PP1 + c];
    AS1[i * PP1 + c] = (a0 + a1) + (a2 + a3);
}

// ---- coalesced column softmax over S1 [5000][256] ----
__global__ void smax_part(const float* __restrict__ S, float* __restrict__ part) {
    int c = threadIdx.x, ch = blockIdx.x;
    const float* p = S + ch * 25 * PP1 + c;
    float m = -3.0e38f;
    #pragma unroll
    for (int r = 0; r < 25; ++r) m = fmaxf(m, p[r * PP1]);
    float s = 0.f;
    #pragma unroll
    for (int r = 0; r < 25; ++r) s += expf(p[r * PP1] - m);
    part[ch * 512 + c] = m;
    part[ch * 512 + 256 + c] = s;
}

// combine chunk partials -> cstat[c] = colmax + ln(colsum).  32 blocks x (8 cols x 32 workers)
__global__ void smax_finish(const float* __restrict__ part, float* __restrict__ cstat) {
    int cg = threadIdx.x >> 5, w = threadIdx.x & 31;
    int c = (blockIdx.x << 3) + cg;
    float m = -3.0e38f;
    for (int ch = w; ch < CHUNKS; ch += 32) m = fmaxf(m, part[ch * 512 + c]);
    float s = 0.f;
    for (int ch = w; ch < CHUNKS; ch += 32) s += part[ch * 512 + 256 + c] * expf(part[ch * 512 + c] - m);
    #pragma unroll
    for (int o = 16; o > 0; o >>= 1) {
        float mo = __shfl_xor(m, o);
        float so = __shfl_xor(s, o);
        float mn = fmaxf(m, mo);
        s = s * expf(m - mn) + so * expf(mo - mn);
        m = mn;
    }
    if (w == 0) cstat[c] = m + logf(s);
}

// normalize in place + entropy + y-pool accumulation (64x64 tiles)
__global__ void smax_norm(float* __restrict__ S, const float* __restrict__ cstat,
                          const float* __restrict__ y, float* __restrict__ y2acc,
                          float* __restrict__ ent) {
    __shared__ float red[256];
    __shared__ float ybuf[4][64];
    int rt = blockIdx.x % 79, ct = blockIdx.x / 79;
    int lc = threadIdx.x & 63, lr = threadIdx.x >> 6;
    int c = (ct << 6) + lc;
    float mxlns = cstat[c];
    float en = 0.f, ys = 0.f;
    #pragma unroll
    for (int k = 0; k < 16; ++k) {
        int r = (rt << 6) + (k << 2) + lr;
        if (r < NN) {
            float v = S[r * PP1 + c];
            float s = expf(v - mxlns);       // = exp(v - mx) / sum
            S[r * PP1 + c] = s;
            en += s * (mxlns - v);           // = -s*ln(s)
            ys = fmaf(s, y[r], ys);
        }
    }
    ybuf[lr][lc] = ys;
    en = bsum256(en, red);                   // syncs cover ybuf visibility
    if (threadIdx.x == 0) atomicAdd(ent, en);
    if (lr == 0) atomicAdd(&y2acc[c], ybuf[0][lc] + ybuf[1][lc] + ybuf[2][lc] + ybuf[3][lc]);
}

// split-K TN GEMM: C[M][N] += scale * A^T B, A: K x M row-major, B: K x N row-major.
__global__ void gemm_tn(const float* __restrict__ A, const float* __restrict__ B,
                        float* __restrict__ C, int M, int N, int K, int kchunk, float scale) {
    __shared__ float sa[32][64];
    __shared__ float sb[32][64];
    int tilesN = N >> 6;
    int tm = (blockIdx.x / tilesN) << 6;
    int tn = (blockIdx.x % tilesN) << 6;
    int k0 = blockIdx.y * kchunk;
    int k1 = min(k0 + kchunk, K);
    int tid = threadIdx.x;
    int tx = (tid & 15) << 2;   // n offset
    int ty = (tid >> 4) << 2;   // m offset
    float acc[4][4] = {};
    for (int kb = k0; kb < k1; kb += 32) {
        #pragma unroll
        for (int t = 0; t < 8; ++t) {
            int idx = tid + (t << 8);
            int r = idx >> 6, cc = idx & 63;
            int k = kb + r;
            sa[r][cc] = (k < k1) ? A[k * M + tm + cc] : 0.f;
            sb[r][cc] = (k < k1) ? B[k * N + tn + cc] : 0.f;
        }
        __syncthreads();
        #pragma unroll
        for (int kk = 0; kk < 32; ++kk) {
            float4 av = *(const float4*)&sa[kk][ty];
            float4 bv = *(const float4*)&sb[kk][tx];
            acc[0][0] = fmaf(av.x, bv.x, acc[0][0]);
            acc[0][1] = fmaf(av.x, bv.y, acc[0][1]);
            acc[0][2] = fmaf(av.x, bv.z, acc[0][2]);
            acc[0][3] = fmaf(av.x, bv.w, acc[0][3]);
            acc[1][0] = fmaf(av.y, bv.x, acc[1][0]);
            acc[1][1] = fmaf(av.y, bv.y, acc[1][1]);
            acc[1][2] = fmaf(av.y, bv.z, acc[1][2]);
            acc[1][3] = fmaf(av.y, bv.w, acc[1][3]);
            acc[2][0] = fmaf(av.z, bv.x, acc[2][0]);
            acc[2][1] = fmaf(av.z, bv.y, acc[2][1]);
            acc[2][2] = fmaf(av.z, bv.z, acc[2][2]);
            acc[2][3] = fmaf(av.z, bv.w, acc[2][3]);
            acc[3][0] = fmaf(av.w, bv.x, acc[3][0]);
            acc[3][1] = fmaf(av.w, bv.y, acc[3][1]);
            acc[3][2] = fmaf(av.w, bv.z, acc[3][2]);
            acc[3][3] = fmaf(av.w, bv.w, acc[3][3]);
        }
        __syncthreads();
    }
    #pragma unroll
    for (int i = 0; i < 4; ++i)
        #pragma unroll
        for (int j = 0; j < 4; ++j)
            atomicAdd(&C[(tm + ty + i) * N + tn + tx + j], acc[i][j] * scale);
}

// small column softmax (S2: 256 rows x 32 cols) + entr + y-pool (yin pre-scale folded in)
__global__ void softmax_col(float* __restrict__ S, int rows, int cols, float* __restrict__ ent,
                            const float* __restrict__ yin, float* __restrict__ yout, float yscale) {
    __shared__ float red[256];
    int p = blockIdx.x, t = threadIdx.x;
    float mx = -3.0e38f;
    for (int r = t; r < rows; r += 256) mx = fmaxf(mx, S[r * cols + p]);
    red[t] = mx; __syncthreads();
    #pragma unroll
    for (int o = 128; o > 0; o >>= 1) {
        if (t < o) red[t] = fmaxf(red[t], red[t + o]);
        __syncthreads();
    }
    mx = red[0]; __syncthreads();
    float sum = 0.f;
    for (int r = t; r < rows; r += 256) sum += expf(S[r * cols + p] - mx);
    sum = bsum256(sum, red);
    float lns = logf(sum), inv = 1.f / sum;
    float en = 0.f, ys = 0.f;
    for (int r = t; r < rows; r += 256) {
        float l = S[r * cols + p];
        float s = expf(l - mx) * inv;
        S[r * cols + p] = s;
        en += s * (mx + lns - l);
        ys = fmaf(s, yin[r], ys);
    }
    en = bsum256(en, red);
    ys = bsum256(ys, red);
    if (t == 0) {
        atomicAdd(ent, en);
        yout[p] = ys * yscale;
    }
}

// out[j,d] = scale * sum_i S[i*scols+j] * Z[i*zcols+d]   (small; x3)
__global__ void pool_t(const float* __restrict__ S, int scols, const float* __restrict__ Z, int zcols,
                       int rows, float scale, float* __restrict__ out) {
    int j = blockIdx.x, d = threadIdx.x;
    float a0 = 0.f, a1 = 0.f, a2 = 0.f, a3 = 0.f;
    int i = 0;
    for (; i + 4 <= rows; i += 4) {
        a0 = fmaf(S[(i + 0) * scols + j], Z[(i + 0) * zcols + d], a0);
        a1 = fmaf(S[(i + 1) * scols + j], Z[(i + 1) * zcols + d], a1);
        a2 = fmaf(S[(i + 2) * scols + j], Z[(i + 2) * zcols + d], a2);
        a3 = fmaf(S[(i + 3) * scols + j], Z[(i + 3) * zcols + d], a3);
    }
    for (; i < rows; ++i) a0 = fmaf(S[i * scols + j], Z[i * zcols + d], a0);
    out[j * zcols + d] = ((a0 + a1) + (a2 + a3)) * scale;
}

// one block per row i of z_r (5288 rows); 256 threads = H.  NO same-address atomics:
// per-row (du^2, res^2) written to dres; reduced by reduce_loss.
__global__ void decoder(const float* __restrict__ z, const float* __restrict__ x2,
                        const float* __restrict__ x3, const float* __restrict__ y,
                        const float* __restrict__ y2acc, const float* __restrict__ y3,
                        const float* __restrict__ W1, const float* __restrict__ W2,
                        const float* __restrict__ b2, const float* __restrict__ cq,
                        float* __restrict__ dres) {
    __shared__ float zrow[DD];
    __shared__ float r3[12];
    int i = blockIdx.x, h = threadIdx.x;
    const float* zr = (i < NN) ? (z + i * DD)
                    : (i < NN + PP1) ? (x2 + (i - NN) * DD)
                    : (x3 + (i - NN - PP1) * DD);
    if (h < DD) zrow[h] = zr[h];
    __syncthreads();
    float a = cq[h];
    #pragma unroll
    for (int k = 0; k < DD; ++k) a = fmaf(zrow[k], W1[(TD + XD + k) * HH + h], a);
    float th = tanhf(a);
    float g1 = 1.f - th * th;
    float w2h = W2[h];
    float pu = w2h * th;
    float pg = w2h * g1 * W1[h];                      // W1[0,h]
    float pl = w2h * (-2.f * th * g1) * cq[HH + h];   // q[h]
    #pragma unroll
    for (int o = 32; o > 0; o >>= 1) {
        pu += __shfl_xor(pu, o);
        pg += __shfl_xor(pg, o);
        pl += __shfl_xor(pl, o);
    }
    int wave = h >> 6, lane = h & 63;
    if (lane == 0) { r3[wave] = pu; r3[4 + wave] = pg; r3[8 + wave] = pl; }
    __syncthreads();
    if (h == 0) {
        float su = r3[0] + r3[1] + r3[2] + r3[3];
        float sg = r3[4] + r3[5] + r3[6] + r3[7];
        float sl = r3[8] + r3[9] + r3[10] + r3[11];
        float u = su + b2[0];
        float yv = (i < NN) ? y[i]
                 : (i < NN + PP1) ? y2acc[i - NN] * Y2SCALE
                 : y3[i - NN - PP1];
        float du = u - yv;
        float res = sg - sl;
        dres[i * 2] = du * du;
        dres[i * 2 + 1] = res * res;
    }
}

// single block: sum dres + combine with entropies -> out[0]
__global__ void reduce_loss(const float* __restrict__ dres, const float* __restrict__ acc,
                            float* __restrict__ out) {
    __shared__ float red[256];
    int t = threadIdx.x;
    float sd = 0.f, sp = 0.f;
    for (int i = t; i < MM; i += 256) {
        sd += dres[i * 2];
        sp += dres[i * 2 + 1];
    }
    sd = bsum256(sd, red);
    sp = bsum256(sp, red);
    if (t == 0)
        out[0] = sd * (1.f / MM) + sp * (1.f / MM)
               + acc[2] * (1.f / (float)(NN * PP1)) + acc[3] * (1.f / (float)(PP1 * PP2));
}

extern "C" void kernel_launch(void* const* d_in, const int* in_sizes, int n_in,
                              void* d_out, int out_size, void* d_ws, size_t ws_size,
                              hipStream_t stream) {
    const float* x0   = (const float*)d_in[0];
    const int*   adj  = (const int*)d_in[1];
    const float* t    = (const float*)d_in[2];
    const float* y    = (const float*)d_in[3];
    const float* Wenc = (const float*)d_in[4];
    const float* Wp1  = (const float*)d_in[5];
    const float* Wp2  = (const float*)d_in[6];
    const float* We1  = (const float*)d_in[7];
    const float* We2  = (const float*)d_in[8];
    const float* W1   = (const float*)d_in[9];
    const float* b1   = (const float*)d_in[10];
    const float* W2   = (const float*)d_in[11];
    const float* b2   = (const float*)d_in[12];

    char* ws = (char*)d_ws;
    float* acc   = (float*)(ws + ACC_OFF);
    int*   deg   = (int*)(ws + DEG_OFF);
    float* y2acc = (float*)(ws + Y2A_OFF);
    float* x2    = (float*)(ws + X2_OFF);
    float* A2    = (float*)(ws + A2_OFF);
    unsigned int* mask = (unsigned int*)(ws + BM_OFF);
    float* part  = (float*)(ws + PART_OFF);
    float* cstat = (float*)(ws + CSTAT_OFF);
    float* XW2   = (float*)(ws + XW2_OFF);
    float* S2    = (float*)(ws + S2_OFF);
    float* ze2   = (float*)(ws + ZE2_OFF);
    float* x3    = (float*)(ws + X3_OFF);
    float* y3    = (float*)(ws + Y3_OFF);
    int*   buck  = (int*)(ws + BUCK_OFF);
    float* zep   = (float*)(ws + ZEP_OFF);
    float* z     = (float*)(ws + Z_OFF);
    float* S1    = (float*)(ws + S1_OFF);
    float* AS1   = (float*)(ws + AS1_OFF);
    float* cq    = (float*)(ws + CQ_OFF);
    float* dres  = (float*)(ws + DRES_OFF);

    hipMemsetAsync(ws, 0, ZERO_BYTES, stream);

    // encoder GEMM + edge dedupe + decoder c/q prep (independent; fused dispatch)
    stage0<<<1564, 256, 0, stream>>>(x0, Wenc, z, adj, mask, buck, deg, t, W1, b1, cq);
    // ze1 = tanh((A @ z) @ We1)  (reassociated)
    gather_z<<<NN, DD, 0, stream>>>(buck, deg, z, zep);
    mm_ip_tanh<<<NN / 4, 256, 0, stream>>>(zep, We1);
    // S1 logits then coalesced column softmax (+ ent + y2 accumulation)
    mm_t<DD, 0><<<(NN * PP1) / 256, 256, 0, stream>>>(z, DD, Wp1, PP1, S1, PP1, NN, PP1, LOG_SCALE);
    smax_part<<<CHUNKS, 256, 0, stream>>>(S1, part);
    smax_finish<<<32, 256, 0, stream>>>(part, cstat);
    smax_norm<<<79 * 4, 256, 0, stream>>>(S1, cstat, y, y2acc, &acc[2]);
    // x2 = S1^T ze1 * (256/5000)   [split-K GEMM, atomic accumulate into zeroed x2]
    gemm_tn<<<dim3(4, 32), 256, 0, stream>>>(S1, zep, x2, PP1, DD, NN, 157, Y2SCALE);
    // A2 = S1^T (A S1)
    gather_as<<<NN, PP1, 0, stream>>>(buck, deg, S1, AS1);
    gemm_tn<<<dim3(16, 16), 256, 0, stream>>>(S1, AS1, A2, PP1, PP1, NN, 313, 1.f);
    // level 2
    mm_t<DD, 0><<<(PP1 * DD) / 256, 256, 0, stream>>>(x2, DD, We2, DD, XW2, DD, PP1, DD, 1.f);
    mm_t<DD, 0><<<(PP1 * PP2) / 256, 256, 0, stream>>>(x2, DD, Wp2, PP2, S2, PP2, PP1, PP2, LOG_SCALE);
    // y3 = (y2acc*Y2SCALE) @ S2 * (32/256): fold Y2SCALE into yscale
    softmax_col<<<PP2, 256, 0, stream>>>(S2, PP1, PP2, &acc[3], y2acc, y3, (32.f / 256.f) * Y2SCALE);
    mm_k256_tanh<<<(PP1 * DD) / 256, 256, 0, stream>>>(A2, XW2, ze2);
    pool_t<<<PP2, DD, 0, stream>>>(S2, PP2, ze2, DD, PP1, 32.f / 256.f, x3);
    // decoder + loss reduce
    decoder<<<MM, 256, 0, stream>>>(z, x2, x3, y, y2acc, y3, W1, W2, b2, cq, dres);
    reduce_loss<<<1, 256, 0, stream>>>(dres, acc, (float*)d_out);
}

// Round 5
// 224.108 us; speedup vs baseline: 11.3115x; 1.4180x over previous
//
#include <hip/hip_runtime.h>
#include <math.h>

#define NN 5000
#define EE 80000
#define FIN 32
#define DD 64
#define XD 3
#define TD 6
#define PP1 256
#define PP2 32
#define HH 256
#define MM (NN + PP1 + PP2)   // 5288
#define CAP 64                // neighbor bucket capacity (Poisson mean 16; P(deg>64) ~ 1e-18)
#define CHUNKS 200            // softmax row chunks (25 rows each)
#define LOG_SCALE 1.4763057f
#define Y2SCALE (256.f / 5000.f)

// A2 split-K: 16 tiles x 40 chunks (kchunk=128); x2 split-K: 4 tiles x 79 chunks (kchunk=64)
#define A2CH 40
#define X2CH 79

// ---------------- workspace layout (bytes) ----------------
#define ACC_OFF   0u           // [2]=ent1 [3]=ent2
#define DEG_OFF   256u         // deg[5000] int -> 20256
#define Y2A_OFF   20256u       // y2 accumulator [256] -> 21280
#define X2_OFF    21280u       // x2 [256][64] -> 86816
#define A2_OFF    86816u       // A2 [256][256] -> 348960
#define BM_OFF    348960u      // bitmask 25M bits -> 3,473,960
#define ZERO_BYTES 3473960u
// aliases inside BM region (bitmask dead after stage0):
#define PART_OFF  348960u      // [200][2][256] f32 -> 758560
#define CSTAT_OFF 758560u      // [256] -> 759584
#define XW2_OFF   760608u      // [256][64] -> 826144
#define S2_OFF    826144u      // [256][32] -> 858912
#define ZE2_OFF   858912u      // [256][64] -> 924448
#define X3_OFF    924448u      // [32][64] -> 932640
#define Y3_OFF    932640u      // [32] -> 932768
// non-zeroed:
#define BUCK_OFF  3473984u     // bucket [5000][64] int -> 4753984
#define ZEP_OFF   4753984u     // zsum/ze1 [5000][64] -> 6033984
#define Z_OFF     6033984u     // z [5000][64] -> 7313984
#define S1_OFF    7313984u     // S1 [5000][256] -> 12433984
#define AS1_OFF   12433984u    // AS1 [5000][256] -> 17553984
#define CQ_OFF    17553984u    // c[256], q[256] -> 17556032
#define DRES_OFF  17556032u    // dres [5288][2] -> 17598336
// split-K partial pools (roomy path only):
#define PA2_OFF   17598336u    // [40][256][256] f32 -> 28084096
#define PX2_OFF   28084096u    // [79][256][64]  f32 -> 33261440
#define WS_ROOMY  33261504u

__device__ __forceinline__ float bsum256(float v, float* red) {
    int t = threadIdx.x;
    red[t] = v; __syncthreads();
    #pragma unroll
    for (int o = 128; o > 0; o >>= 1) {
        if (t < o) red[t] += red[t + o];
        __syncthreads();
    }
    float r = red[0]; __syncthreads();
    return r;
}

// fused: encoder GEMM (blocks 0..1249) | edge dedupe (1250..1562) | prep c/q (1563)
__global__ void stage0(const float* __restrict__ x0, const float* __restrict__ Wenc,
                       float* __restrict__ z,
                       const int* __restrict__ adj, unsigned int* __restrict__ mask,
                       int* __restrict__ bucket, int* __restrict__ deg,
                       const float* __restrict__ t, const float* __restrict__ W1,
                       const float* __restrict__ b1, float* __restrict__ cq) {
    __shared__ float te[TD];
    int b = blockIdx.x;
    if (b < 1250) {
        int gid = b * 256 + threadIdx.x;
        int i = gid >> 6, j = gid & 63;
        float s = 0.f;
        #pragma unroll
        for (int k = 0; k < FIN; ++k) s = fmaf(x0[i * FIN + k], Wenc[k * (DD + XD) + j], s);
        z[i * DD + j] = tanhf(s) * LOG_SCALE;
    } else if (b < 1563) {
        int e = (b - 1250) * 256 + threadIdx.x;
        if (e < EE) {
            int i = adj[e], j = adj[EE + e];
            unsigned int key = (unsigned int)(i * NN + j);
            unsigned int bit = 1u << (key & 31u);
            unsigned int old = atomicOr(&mask[key >> 5], bit);
            if (!(old & bit)) {
                int slot = atomicAdd(&deg[i], 1);
                if (slot < CAP) bucket[i * CAP + slot] = j;
            }
        }
    } else {
        int h = threadIdx.x;
        if (h == 0) {
            float t0 = t[0];
            te[0] = t0 / 1e2f;
            te[1] = t0 / 1e3f;
            te[2] = t0 / 1e4f;
            te[3] = logf(t0 * 100.f + 1.f);
            te[4] = logf(t0 * 10.f + 1.f);
            te[5] = logf(t0 + 1.f);
        }
        __syncthreads();
        float c = b1[h];
        #pragma unroll
        for (int j = 0; j < TD; ++j) c = fmaf(te[j], W1[j * HH + h], c);
        float q = 0.f;
        #pragma unroll
        for (int j = 1; j < TD + XD; ++j) { float w = W1[j * HH + h]; q = fmaf(w, w, q); }
        cq[h] = c;
        cq[HH + h] = q;
    }
}

// small matmul, compile-time K (full unroll)
template<int KK, int ACT>
__global__ void mm_t(const float* __restrict__ A, int lda, const float* __restrict__ B, int ldb,
                     float* __restrict__ C, int ldc, int Mr, int Nc, float scale) {
    int gid = blockIdx.x * blockDim.x + threadIdx.x;
    if (gid >= Mr * Nc) return;
    int i = gid / Nc, j = gid - i * Nc;
    const float* a = A + i * lda;
    const float* bp = B + j;
    float s = 0.f;
    #pragma unroll
    for (int k = 0; k < KK; ++k) s = fmaf(a[k], bp[k * ldb], s);
    if (ACT) s = tanhf(s);
    C[i * ldc + j] = s * scale;
}

// fused gather_z + (A@z)@We1 + tanh: 4 rows per block, one wave per row
__global__ void gather_embed(const int* __restrict__ bucket, const int* __restrict__ deg,
                             const float* __restrict__ z, const float* __restrict__ We1,
                             float* __restrict__ zep) {
    __shared__ float zs[4][DD];
    int w = threadIdx.x >> 6, d = threadIdx.x & 63;
    int i = (blockIdx.x << 2) + w;
    int n = min(deg[i], CAP);
    const int* bk = bucket + i * CAP;
    float a0 = 0.f, a1 = 0.f, a2 = 0.f, a3 = 0.f;
    int s = 0;
    for (; s + 4 <= n; s += 4) {
        a0 += z[bk[s] * DD + d];
        a1 += z[bk[s + 1] * DD + d];
        a2 += z[bk[s + 2] * DD + d];
        a3 += z[bk[s + 3] * DD + d];
    }
    for (; s < n; ++s) a0 += z[bk[s] * DD + d];
    zs[w][d] = (a0 + a1) + (a2 + a3);
    __syncthreads();
    float acc = 0.f;
    #pragma unroll
    for (int k = 0; k < DD; ++k) acc = fmaf(zs[w][k], We1[k * DD + d], acc);
    zep[i * DD + d] = tanhf(acc);
}

// AS1[i,c] = sum_{j in N(i)} S1[j,c]
__global__ void gather_as(const int* __restrict__ bucket, const int* __restrict__ deg,
                          const float* __restrict__ S1, float* __restrict__ AS1) {
    int i = blockIdx.x, c = threadIdx.x;
    int n = min(deg[i], CAP);
    const int* bk = bucket + i * CAP;
    float a0 = 0.f, a1 = 0.f, a2 = 0.f, a3 = 0.f;
    int s = 0;
    for (; s + 4 <= n; s += 4) {
        a0 += S1[bk[s] * PP1 + c];
        a1 += S1[bk[s + 1] * PP1 + c];
        a2 += S1[bk[s + 2] * PP1 + c];
        a3 += S1[bk[s + 3] * PP1 + c];
    }
    for (; s < n; ++s) a0 += S1[bk[s] * PP1 + c];
    AS1[i * PP1 + c] = (a0 + a1) + (a2 + a3);
}

// ---- coalesced column softmax over S1 [5000][256] ----
__global__ void smax_part(const float* __restrict__ S, float* __restrict__ part) {
    int c = threadIdx.x, ch = blockIdx.x;
    const float* p = S + ch * 25 * PP1 + c;
    float m = -3.0e38f;
    #pragma unroll
    for (int r = 0; r < 25; ++r) m = fmaxf(m, p[r * PP1]);
    float s = 0.f;
    #pragma unroll
    for (int r = 0; r < 25; ++r) s += expf(p[r * PP1] - m);
    part[ch * 512 + c] = m;
    part[ch * 512 + 256 + c] = s;
}

__global__ void smax_finish(const float* __restrict__ part, float* __restrict__ cstat) {
    int cg = threadIdx.x >> 5, w = threadIdx.x & 31;
    int c = (blockIdx.x << 3) + cg;
    float m = -3.0e38f;
    for (int ch = w; ch < CHUNKS; ch += 32) m = fmaxf(m, part[ch * 512 + c]);
    float s = 0.f;
    for (int ch = w; ch < CHUNKS; ch += 32) s += part[ch * 512 + 256 + c] * expf(part[ch * 512 + c] - m);
    #pragma unroll
    for (int o = 16; o > 0; o >>= 1) {
        float mo = __shfl_xor(m, o);
        float so = __shfl_xor(s, o);
        float mn = fmaxf(m, mo);
        s = s * expf(m - mn) + so * expf(mo - mn);
        m = mn;
    }
    if (w == 0) cstat[c] = m + logf(s);
}

__global__ void smax_norm(float* __restrict__ S, const float* __restrict__ cstat,
                          const float* __restrict__ y, float* __restrict__ y2acc,
                          float* __restrict__ ent) {
    __shared__ float red[256];
    __shared__ float ybuf[4][64];
    int rt = blockIdx.x % 79, ct = blockIdx.x / 79;
    int lc = threadIdx.x & 63, lr = threadIdx.x >> 6;
    int c = (ct << 6) + lc;
    float mxlns = cstat[c];
    float en = 0.f, ys = 0.f;
    #pragma unroll
    for (int k = 0; k < 16; ++k) {
        int r = (rt << 6) + (k << 2) + lr;
        if (r < NN) {
            float v = S[r * PP1 + c];
            float s = expf(v - mxlns);
            S[r * PP1 + c] = s;
            en += s * (mxlns - v);
            ys = fmaf(s, y[r], ys);
        }
    }
    ybuf[lr][lc] = ys;
    en = bsum256(en, red);
    if (threadIdx.x == 0) atomicAdd(ent, en);
    if (lr == 0) atomicAdd(&y2acc[c], ybuf[0][lc] + ybuf[1][lc] + ybuf[2][lc] + ybuf[3][lc]);
}

// fused split-K TN GEMM, partials (no atomics).
// blocks 0..639: A2 partials (tile=b&15, chunk=b>>4, kchunk=128)
// blocks 640..955: x2 partials (tile=b2&3, chunk=b2>>2, kchunk=64)
__global__ __launch_bounds__(256) void gemm_fused(
        const float* __restrict__ S1, const float* __restrict__ AS1,
        const float* __restrict__ zep, float* __restrict__ PA2, float* __restrict__ PX2) {
    __shared__ float sa[32][64];
    __shared__ float sb[32][64];
    int b = blockIdx.x;
    const float* B;
    float* dst;
    int tm, tn, k0, k1, NB;
    if (b < 640) {
        int tile = b & 15, chunk = b >> 4;
        tm = (tile >> 2) << 6; tn = (tile & 3) << 6;
        k0 = chunk * 128; k1 = min(k0 + 128, NN);
        B = AS1; NB = PP1;
        dst = PA2 + chunk * (PP1 * PP1);
    } else {
        int b2 = b - 640;
        int tile = b2 & 3, chunk = b2 >> 2;
        tm = tile << 6; tn = 0;
        k0 = chunk * 64; k1 = min(k0 + 64, NN);
        B = zep; NB = DD;
        dst = PX2 + chunk * (PP1 * DD);
    }
    int tid = threadIdx.x;
    int tx = (tid & 15) << 2;
    int ty = (tid >> 4) << 2;
    int r0 = tid >> 4, c0 = (tid & 15) << 2;          // float4 slot 0
    int r1 = (tid + 256) >> 4, c1 = c0;               // float4 slot 1
    float acc[4][4] = {};
    const float4 z4 = make_float4(0.f, 0.f, 0.f, 0.f);
    for (int kb = k0; kb < k1; kb += 32) {
        int ka0 = kb + r0, ka1 = kb + r1;
        *(float4*)&sa[r0][c0] = (ka0 < k1) ? *(const float4*)&S1[ka0 * PP1 + tm + c0] : z4;
        *(float4*)&sa[r1][c1] = (ka1 < k1) ? *(const float4*)&S1[ka1 * PP1 + tm + c1] : z4;
        *(float4*)&sb[r0][c0] = (ka0 < k1) ? *(const float4*)&B[ka0 * NB + tn + c0] : z4;
        *(float4*)&sb[r1][c1] = (ka1 < k1) ? *(const float4*)&B[ka1 * NB + tn + c1] : z4;
        __syncthreads();
        #pragma unroll
        for (int kk = 0; kk < 32; ++kk) {
            float4 av = *(const float4*)&sa[kk][ty];
            float4 bv = *(const float4*)&sb[kk][tx];
            acc[0][0] = fmaf(av.x, bv.x, acc[0][0]);
            acc[0][1] = fmaf(av.x, bv.y, acc[0][1]);
            acc[0][2] = fmaf(av.x, bv.z, acc[0][2]);
            acc[0][3] = fmaf(av.x, bv.w, acc[0][3]);
            acc[1][0] = fmaf(av.y, bv.x, acc[1][0]);
            acc[1][1] = fmaf(av.y, bv.y, acc[1][1]);
            acc[1][2] = fmaf(av.y, bv.z, acc[1][2]);
            acc[1][3] = fmaf(av.y, bv.w, acc[1][3]);
            acc[2][0] = fmaf(av.z, bv.x, acc[2][0]);
            acc[2][1] = fmaf(av.z, bv.y, acc[2][1]);
            acc[2][2] = fmaf(av.z, bv.z, acc[2][2]);
            acc[2][3] = fmaf(av.z, bv.w, acc[2][3]);
            acc[3][0] = fmaf(av.w, bv.x, acc[3][0]);
            acc[3][1] = fmaf(av.w, bv.y, acc[3][1]);
            acc[3][2] = fmaf(av.w, bv.z, acc[3][2]);
            acc[3][3] = fmaf(av.w, bv.w, acc[3][3]);
        }
        __syncthreads();
    }
    #pragma unroll
    for (int i = 0; i < 4; ++i)
        *(float4*)&dst[(tm + ty + i) * NB + tn + tx] =
            make_float4(acc[i][0], acc[i][1], acc[i][2], acc[i][3]);
}

// sum partials -> A2 (scale 1) and x2 (scale Y2SCALE). grid 320x256 = 81920 threads.
__global__ void reduce_parts(const float* __restrict__ PA2, const float* __restrict__ PX2,
                             float* __restrict__ A2, float* __restrict__ x2) {
    int idx = blockIdx.x * 256 + threadIdx.x;
    if (idx < PP1 * PP1) {
        float s = 0.f;
        #pragma unroll 8
        for (int c = 0; c < A2CH; ++c) s += PA2[c * (PP1 * PP1) + idx];
        A2[idx] = s;
    } else {
        int e = idx - PP1 * PP1;
        float s = 0.f;
        #pragma unroll 8
        for (int c = 0; c < X2CH; ++c) s += PX2[c * (PP1 * DD) + e];
        x2[e] = s * Y2SCALE;
    }
}

// fallback (small ws): atomic split-K TN GEMM (round-4 version)
__global__ void gemm_tn(const float* __restrict__ A, const float* __restrict__ B,
                        float* __restrict__ C, int M, int N, int K, int kchunk, float scale) {
    __shared__ float sa[32][64];
    __shared__ float sb[32][64];
    int tilesN = N >> 6;
    int tm = (blockIdx.x / tilesN) << 6;
    int tn = (blockIdx.x % tilesN) << 6;
    int k0 = blockIdx.y * kchunk;
    int k1 = min(k0 + kchunk, K);
    int tid = threadIdx.x;
    int tx = (tid & 15) << 2;
    int ty = (tid >> 4) << 2;
    float acc[4][4] = {};
    for (int kb = k0; kb < k1; kb += 32) {
        #pragma unroll
        for (int t = 0; t < 8; ++t) {
            int idx = tid + (t << 8);
            int r = idx >> 6, cc = idx & 63;
            int k = kb + r;
            sa[r][cc] = (k < k1) ? A[k * M + tm + cc] : 0.f;
            sb[r][cc] = (k < k1) ? B[k * N + tn + cc] : 0.f;
        }
        __syncthreads();
        #pragma unroll
        for (int kk = 0; kk < 32; ++kk) {
            float4 av = *(const float4*)&sa[kk][ty];
            float4 bv = *(const float4*)&sb[kk][tx];
            acc[0][0] = fmaf(av.x, bv.x, acc[0][0]);
            acc[0][1] = fmaf(av.x, bv.y, acc[0][1]);
            acc[0][2] = fmaf(av.x, bv.z, acc[0][2]);
            acc[0][3] = fmaf(av.x, bv.w, acc[0][3]);
            acc[1][0] = fmaf(av.y, bv.x, acc[1][0]);
            acc[1][1] = fmaf(av.y, bv.y, acc[1][1]);
            acc[1][2] = fmaf(av.y, bv.z, acc[1][2]);
            acc[1][3] = fmaf(av.y, bv.w, acc[1][3]);
            acc[2][0] = fmaf(av.z, bv.x, acc[2][0]);
            acc[2][1] = fmaf(av.z, bv.y, acc[2][1]);
            acc[2][2] = fmaf(av.z, bv.z, acc[2][2]);
            acc[2][3] = fmaf(av.z, bv.w, acc[2][3]);
            acc[3][0] = fmaf(av.w, bv.x, acc[3][0]);
            acc[3][1] = fmaf(av.w, bv.y, acc[3][1]);
            acc[3][2] = fmaf(av.w, bv.z, acc[3][2]);
            acc[3][3] = fmaf(av.w, bv.w, acc[3][3]);
        }
        __syncthreads();
    }
    #pragma unroll
    for (int i = 0; i < 4; ++i)
        #pragma unroll
        for (int j = 0; j < 4; ++j)
            atomicAdd(&C[(tm + ty + i) * N + tn + tx + j], acc[i][j] * scale);
}

// fused XW2 = x2@We2 (blocks 0..63) and S2 logits = x2@Wp2*LS (blocks 64..95)
__global__ void mm2_fused(const float* __restrict__ x2, const float* __restrict__ We2,
                          const float* __restrict__ Wp2, float* __restrict__ XW2,
                          float* __restrict__ S2) {
    int gid = blockIdx.x * 256 + threadIdx.x;
    if (gid < PP1 * DD) {
        int i = gid >> 6, j = gid & 63;
        float s = 0.f;
        #pragma unroll
        for (int k = 0; k < DD; ++k) s = fmaf(x2[i * DD + k], We2[k * DD + j], s);
        XW2[gid] = s;
    } else {
        int e = gid - PP1 * DD;
        int i = e >> 5, j = e & 31;
        float s = 0.f;
        #pragma unroll
        for (int k = 0; k < DD; ++k) s = fmaf(x2[i * DD + k], Wp2[k * PP2 + j], s);
        S2[e] = s * LOG_SCALE;
    }
}

// fused: S2 softmax (+ent+y3) on blocks 0..31 | ze2 = tanh(A2@XW2) on blocks 32..95
__global__ void level2b(float* __restrict__ S2, float* __restrict__ ent,
                        const float* __restrict__ y2acc, float* __restrict__ y3,
                        const float* __restrict__ A2, const float* __restrict__ XW2,
                        float* __restrict__ ze2) {
    __shared__ float red[256];
    int t = threadIdx.x;
    if (blockIdx.x < PP2) {
        int p = blockIdx.x;
        float l = S2[t * PP2 + p];   // 256 rows, thread = row
        red[t] = l; __syncthreads();
        #pragma unroll
        for (int o = 128; o > 0; o >>= 1) {
            if (t < o) red[t] = fmaxf(red[t], red[t + o]);
            __syncthreads();
        }
        float mx = red[0]; __syncthreads();
        float ex = expf(l - mx);
        float sum = bsum256(ex, red);
        float lns = logf(sum), inv = 1.f / sum;
        float s = ex * inv;
        S2[t * PP2 + p] = s;
        float en = s * (mx + lns - l);
        float ys = s * y2acc[t];
        en = bsum256(en, red);
        ys = bsum256(ys, red);
        if (t == 0) {
            atomicAdd(ent, en);
            y3[p] = ys * ((32.f / 256.f) * Y2SCALE);
        }
    } else {
        int gid = (blockIdx.x - PP2) * 256 + t;
        int i = gid >> 6, j = gid & 63;
        const float* a = A2 + i * PP1;
        float s = 0.f;
        #pragma unroll 16
        for (int k = 0; k < PP1; ++k) s = fmaf(a[k], XW2[k * DD + j], s);
        ze2[gid] = tanhf(s);
    }
}

// x3[j,d] = (32/256) * sum_i S2[i,j]*ze2[i,d]; 32 blocks x 256 (4-way K split in LDS)
__global__ void pool_x3(const float* __restrict__ S2, const float* __restrict__ ze2,
                        float* __restrict__ x3) {
    __shared__ float pr[4][64];
    int j = blockIdx.x;
    int d = threadIdx.x & 63, q = threadIdx.x >> 6;
    float a = 0.f;
    #pragma unroll 4
    for (int i = q * 64; i < q * 64 + 64; ++i)
        a = fmaf(S2[i * PP2 + j], ze2[i * DD + d], a);
    pr[q][d] = a;
    __syncthreads();
    if (q == 0) x3[j * DD + d] = (pr[0][d] + pr[1][d] + pr[2][d] + pr[3][d]) * (32.f / 256.f);
}

// decoder: 8 rows per block (661 blocks x 256 threads = H)
__global__ __launch_bounds__(256) void decoder8(
        const float* __restrict__ z, const float* __restrict__ x2,
        const float* __restrict__ x3, const float* __restrict__ y,
        const float* __restrict__ y2acc, const float* __restrict__ y3,
        const float* __restrict__ W1, const float* __restrict__ W2,
        const float* __restrict__ b2, const float* __restrict__ cq,
        float* __restrict__ dres) {
    __shared__ float zr[8][DD];
    __shared__ float rw[8][3][4];
    int t = threadIdx.x;
    int i0 = blockIdx.x << 3;
    #pragma unroll
    for (int e = t; e < 512; e += 256) {
        int r = e >> 6, d = e & 63;
        int i = i0 + r;
        float v;
        if (i < NN) v = z[i * DD + d];
        else if (i < NN + PP1) v = x2[(i - NN) * DD + d];
        else v = x3[(i - NN - PP1) * DD + d];
        zr[r][d] = v;
    }
    __syncthreads();
    int h = t;
    float c0 = cq[h];
    float a[8];
    #pragma unroll
    for (int r = 0; r < 8; ++r) a[r] = c0;
    #pragma unroll 8
    for (int k = 0; k < DD; ++k) {
        float w = W1[(TD + XD + k) * HH + h];
        #pragma unroll
        for (int r = 0; r < 8; ++r) a[r] = fmaf(zr[r][k], w, a[r]);
    }
    float w2h = W2[h], w1h = W1[h], qh = cq[HH + h];
    float pu[8], pg[8], pl[8];
    #pragma unroll
    for (int r = 0; r < 8; ++r) {
        float th = tanhf(a[r]);
        float g1 = 1.f - th * th;
        pu[r] = w2h * th;
        pg[r] = w2h * g1 * w1h;
        pl[r] = w2h * (-2.f * th * g1) * qh;
    }
    #pragma unroll
    for (int o = 32; o > 0; o >>= 1) {
        #pragma unroll
        for (int r = 0; r < 8; ++r) {
            pu[r] += __shfl_xor(pu[r], o);
            pg[r] += __shfl_xor(pg[r], o);
            pl[r] += __shfl_xor(pl[r], o);
        }
    }
    int wave = t >> 6, lane = t & 63;
    if (lane == 0) {
        #pragma unroll
        for (int r = 0; r < 8; ++r) {
            rw[r][0][wave] = pu[r];
            rw[r][1][wave] = pg[r];
            rw[r][2][wave] = pl[r];
        }
    }
    __syncthreads();
    if (t < 8) {
        int r = t, i = i0 + r;
        float su = rw[r][0][0] + rw[r][0][1] + rw[r][0][2] + rw[r][0][3];
        float sg = rw[r][1][0] + rw[r][1][1] + rw[r][1][2] + rw[r][1][3];
        float sl = rw[r][2][0] + rw[r][2][1] + rw[r][2][2] + rw[r][2][3];
        float u = su + b2[0];
        float yv = (i < NN) ? y[i]
                 : (i < NN + PP1) ? y2acc[i - NN] * Y2SCALE
                 : y3[i - NN - PP1];
        float du = u - yv;
        float res = sg - sl;
        dres[i * 2] = du * du;
        dres[i * 2 + 1] = res * res;
    }
}

__global__ void reduce_loss(const float* __restrict__ dres, const float* __restrict__ acc,
                            float* __restrict__ out) {
    __shared__ float red[256];
    int t = threadIdx.x;
    float sd = 0.f, sp = 0.f;
    for (int i = t; i < MM; i += 256) {
        sd += dres[i * 2];
        sp += dres[i * 2 + 1];
    }
    sd = bsum256(sd, red);
    sp = bsum256(sp, red);
    if (t == 0)
        out[0] = sd * (1.f / MM) + sp * (1.f / MM)
               + acc[2] * (1.f / (float)(NN * PP1)) + acc[3] * (1.f / (float)(PP1 * PP2));
}

extern "C" void kernel_launch(void* const* d_in, const int* in_sizes, int n_in,
                              void* d_out, int out_size, void* d_ws, size_t ws_size,
                              hipStream_t stream) {
    const float* x0   = (const float*)d_in[0];
    const int*   adj  = (const int*)d_in[1];
    const float* t    = (const float*)d_in[2];
    const float* y    = (const float*)d_in[3];
    const float* Wenc = (const float*)d_in[4];
    const float* Wp1  = (const float*)d_in[5];
    const float* Wp2  = (const float*)d_in[6];
    const float* We1  = (const float*)d_in[7];
    const float* We2  = (const float*)d_in[8];
    const float* W1   = (const float*)d_in[9];
    const float* b1   = (const float*)d_in[10];
    const float* W2   = (const float*)d_in[11];
    const float* b2   = (const float*)d_in[12];

    char* ws = (char*)d_ws;
    float* acc   = (float*)(ws + ACC_OFF);
    int*   deg   = (int*)(ws + DEG_OFF);
    float* y2acc = (float*)(ws + Y2A_OFF);
    float* x2    = (float*)(ws + X2_OFF);
    float* A2    = (float*)(ws + A2_OFF);
    unsigned int* mask = (unsigned int*)(ws + BM_OFF);
    float* part  = (float*)(ws + PART_OFF);
    float* cstat = (float*)(ws + CSTAT_OFF);
    float* XW2   = (float*)(ws + XW2_OFF);
    float* S2    = (float*)(ws + S2_OFF);
    float* ze2   = (float*)(ws + ZE2_OFF);
    float* x3    = (float*)(ws + X3_OFF);
    float* y3    = (float*)(ws + Y3_OFF);
    int*   buck  = (int*)(ws + BUCK_OFF);
    float* zep   = (float*)(ws + ZEP_OFF);
    float* z     = (float*)(ws + Z_OFF);
    float* S1    = (float*)(ws + S1_OFF);
    float* AS1   = (float*)(ws + AS1_OFF);
    float* cq    = (float*)(ws + CQ_OFF);
    float* dres  = (float*)(ws + DRES_OFF);
    float* PA2   = (float*)(ws + PA2_OFF);
    float* PX2   = (float*)(ws + PX2_OFF);

    hipMemsetAsync(ws, 0, ZERO_BYTES, stream);

    stage0<<<1564, 256, 0, stream>>>(x0, Wenc, z, adj, mask, buck, deg, t, W1, b1, cq);
    gather_embed<<<NN / 4, 256, 0, stream>>>(buck, deg, z, We1, zep);
    mm_t<DD, 0><<<(NN * PP1) / 256, 256, 0, stream>>>(z, DD, Wp1, PP1, S1, PP1, NN, PP1, LOG_SCALE);
    smax_part<<<CHUNKS, 256, 0, stream>>>(S1, part);
    smax_finish<<<32, 256, 0, stream>>>(part, cstat);
    smax_norm<<<79 * 4, 256, 0, stream>>>(S1, cstat, y, y2acc, &acc[2]);
    gather_as<<<NN, PP1, 0, stream>>>(buck, deg, S1, AS1);
    if (ws_size >= WS_ROOMY) {
        gemm_fused<<<640 + 316, 256, 0, stream>>>(S1, AS1, zep, PA2, PX2);
        reduce_parts<<<320, 256, 0, stream>>>(PA2, PX2, A2, x2);
    } else {
        gemm_tn<<<dim3(4, 32), 256, 0, stream>>>(S1, zep, x2, PP1, DD, NN, 157, Y2SCALE);
        gemm_tn<<<dim3(16, 16), 256, 0, stream>>>(S1, AS1, A2, PP1, PP1, NN, 313, 1.f);
    }
    mm2_fused<<<96, 256, 0, stream>>>(x2, We2, Wp2, XW2, S2);
    level2b<<<96, 256, 0, stream>>>(S2, &acc[3], y2acc, y3, A2, XW2, ze2);
    pool_x3<<<PP2, 256, 0, stream>>>(S2, ze2, x3);
    decoder8<<<MM / 8, 256, 0, stream>>>(z, x2, x3, y, y2acc, y3, W1, W2, b2, cq, dres);
    reduce_loss<<<1, 256, 0, stream>>>(dres, acc, (float*)d_out);
}